// Round 7
// baseline (190.913 us; speedup 1.0000x reference)
//
#include <hip/hip_runtime.h>
#include <math.h>

#define BB 16
#define CC 256
#define HALF 128
#define HW 6400
#define OCH 127   // HALF-1
#define ICH 129   // HALF+1
#define BN_EPS 1e-5f
#define PIX 64    // pixels per block

// ---------------- kernel 1: per-(b,c) spatial mean (float4) ----------------
__global__ __launch_bounds__(256) void k_means(const float* __restrict__ x1,
                                               float* __restrict__ means) {
    int bc = blockIdx.x;
    const float4* p = (const float4*)(x1 + (size_t)bc * HW);
    float s = 0.f;
    for (int i = threadIdx.x; i < HW / 4; i += 256) {
        float4 v = p[i];
        s += (v.x + v.y) + (v.z + v.w);
    }
    #pragma unroll
    for (int off = 32; off; off >>= 1) s += __shfl_down(s, off, 64);
    __shared__ float red[4];
    int lane = threadIdx.x & 63, w = threadIdx.x >> 6;
    if (lane == 0) red[w] = s;
    __syncthreads();
    if (threadIdx.x == 0) {
        float t = red[0] + red[1] + red[2] + red[3];
        means[bc] = t * (1.0f / HW);
    }
}

// ---------------- kernel 2: ECA conv + sigmoid + top-k selection ----------------
__global__ __launch_bounds__(256) void k_select(const float* __restrict__ means,
                                                const float* __restrict__ eca_w,
                                                int* __restrict__ posidx,
                                                int* __restrict__ negidx) {
    int b = blockIdx.x;
    int c = threadIdx.x;
    __shared__ float m[CC];
    __shared__ float s[CC];
    __shared__ int flag[CC];
    m[c] = means[b * CC + c];
    __syncthreads();
    float y = 0.f;
    #pragma unroll
    for (int k = 0; k < 5; k++) {
        int cc = c + k - 2;
        float mv = (cc >= 0 && cc < CC) ? m[cc] : 0.f;
        y += eca_w[k] * mv;
    }
    float sc = 1.f / (1.f + expf(-y));
    s[c] = sc;
    __syncthreads();
    int rank = 0;
    for (int j = 0; j < CC; j++) {
        float sj = s[j];
        rank += (sj > sc) || (sj == sc && j < c);
    }
    int ispos = (rank < HALF) ? 1 : 0;
    flag[c] = ispos;
    __syncthreads();
    int pre = 0;
    for (int j = 0; j < c; j++) pre += flag[j];
    if (ispos) posidx[b * HALF + pre] = c;
    else       negidx[b * HALF + (c - pre)] = c;
}

// ---------------- kernel 3: transpose conv_w, pad to 128 cols, zero tail ----
__global__ __launch_bounds__(256) void k_wt(const float* __restrict__ cw,
                                            float* __restrict__ WT) {
    for (int idx = threadIdx.x + blockIdx.x * 256; idx < ICH * 128; idx += 256 * gridDim.x) {
        int i = idx / 128, o = idx % 128;
        WT[idx] = (o < OCH) ? cw[o * ICH + i] : 0.f;
    }
}

// ---------------- kernel 4: main fused kernel (R3 structure, pipelined) ----
// 256 threads = 4 waves, 64 pixels/block. Phase B: global re-gather
// (L1/L2-hot), 8-deep v-load pipelining, x0 copy software-pipelined
// one chunk ahead of its store through the FMA bursts.
__global__ __launch_bounds__(256) void k_main(const float* __restrict__ x0,
                                              const float* __restrict__ x1,
                                              const float* __restrict__ WT,
                                              const int* __restrict__ posidx,
                                              const int* __restrict__ negidx,
                                              const float* __restrict__ bn_gamma,
                                              const float* __restrict__ bn_beta,
                                              const float* __restrict__ bn_mean,
                                              const float* __restrict__ bn_var,
                                              float* __restrict__ out) {
    int blk = blockIdx.x;
    int b = blk / (HW / PIX);
    int tile = blk % (HW / PIX);
    int p0 = tile * PIX;
    int tid = threadIdx.x;
    int q = tid & 15;          // float4 chunk
    int cgrp = tid >> 4;       // 0..15 channel subgroup
    int lane = tid & 63;
    int w = tid >> 6;          // 0..3

    __shared__ float snegA[16 * PIX];   // per-cgrp partial neg sums
    __shared__ float mlds[PIX];         // per-pixel neg mean

    const float* x1b = x1 + (size_t)b * CC * HW;
    const float* x0b = x0 + (size_t)b * CC * HW;
    float* outb = out + (size_t)b * 2 * CC * HW;
    const int* pidx = posidx + b * HALF;
    const int* nidx = negidx + b * HALF;

    // ---- phase A: pos gather + direct + neg gather, all float4 ----
    float4 vs = make_float4(0.f, 0.f, 0.f, 0.f);
    #pragma unroll
    for (int s = 0; s < 8; s++) {
        int j = s * 16 + cgrp;
        int cjs = pidx[j];
        int cns = nidx[j];
        const float4* pp = (const float4*)(x1b + (size_t)cjs * HW + p0);
        const float4* pd = (const float4*)(x1b + (size_t)j * HW + p0);
        const float4* pn = (const float4*)(x1b + (size_t)cns * HW + p0);
        float4 vp = pp[q];
        float4 vd = pd[q];
        float4 vn = pn[q];
        float4 so = make_float4(vd.x + vp.x, vd.y + vp.y, vd.z + vp.z, vd.w + vp.w);
        ((float4*)(outb + (size_t)(CC + j) * HW + p0))[q] = so;
        vs.x += vn.x; vs.y += vn.y; vs.z += vn.z; vs.w += vn.w;
    }
    *(float4*)&snegA[cgrp * PIX + q * 4] = vs;
    __syncthreads();

    // ---- neg mean (threads 0..63), out row CC+HALF, mean to LDS ----
    if (tid < 64) {
        float m = 0.f;
        #pragma unroll
        for (int k = 0; k < 16; k++) m += snegA[k * PIX + tid];
        m *= (1.0f / HALF);
        mlds[tid] = m;
        outb[(size_t)(CC + HALF) * HW + p0 + tid] = x1b[(size_t)HALF * HW + p0 + tid] + m;
    }
    __syncthreads();

    // ---- phase B: z[32] accumulate (global gather, cache-hot) with the
    //      x0 float4 copy software-pipelined one chunk ahead ----
    int sg = __builtin_amdgcn_readfirstlane(w);
    const float* wbase = WT + sg * 32;
    int p = p0 + lane;
    float z[32];
    #pragma unroll
    for (int k = 0; k < 32; k++) z[k] = 0.f;

    // chunk mapping: fid = s*256 + tid -> channel c0 = fid>>4, q0 = fid&15
    int c0 = tid >> 4;                 // chunk 0 channel for this thread
    int q0 = tid & 15;
    float4 pend = ((const float4*)(x0b + (size_t)c0 * HW + p0))[q0];

    for (int s = 0; s < 16; s++) {
        #pragma unroll
        for (int ii = 0; ii < 8; ii++) {
            int i = s * 8 + ii;
            int c = pidx[i];                       // uniform -> s_load
            float v = x1b[(size_t)c * HW + p];     // 256B coalesced per wave
            const float* wc = wbase + i * 128;     // uniform -> s_load
            #pragma unroll
            for (int k = 0; k < 32; k++) z[k] += wc[k] * v;
        }
        // retire chunk s, start chunk s+1
        int cs = (s * 256 + tid) >> 4;
        ((float4*)(outb + (size_t)cs * HW + p0))[q0] = pend;
        if (s < 15) {
            int cn = ((s + 1) * 256 + tid) >> 4;
            pend = ((const float4*)(x0b + (size_t)cn * HW + p0))[q0];
        }
    }
    {   // mean contribution (input row 128)
        float v = mlds[lane];
        const float* wc = wbase + HALF * 128;
        #pragma unroll
        for (int k = 0; k < 32; k++) z[k] += wc[k] * v;
    }

    // ---- epilogue: BN + leaky + residual for o = sg*32 + k ----
    #pragma unroll
    for (int k = 0; k < 32; k++) {
        int o = sg * 32 + k;
        if (o < OCH) {
            float scale = bn_gamma[o] * rsqrtf(bn_var[o] + BN_EPS);
            float zz = (z[k] - bn_mean[o]) * scale + bn_beta[o];
            float t2 = zz > 0.f ? zz : 0.1f * zz;
            outb[(size_t)(CC + HALF + 1 + o) * HW + p] =
                x1b[(size_t)(HALF + 1 + o) * HW + p] + t2;
        }
    }
}

extern "C" void kernel_launch(void* const* d_in, const int* in_sizes, int n_in,
                              void* d_out, int out_size, void* d_ws, size_t ws_size,
                              hipStream_t stream) {
    const float* x0      = (const float*)d_in[0];
    const float* x1      = (const float*)d_in[1];
    const float* eca_w   = (const float*)d_in[2];
    const float* conv_w  = (const float*)d_in[3];
    const float* bn_gamma= (const float*)d_in[4];
    const float* bn_beta = (const float*)d_in[5];
    const float* bn_mean = (const float*)d_in[6];
    const float* bn_var  = (const float*)d_in[7];
    float* out = (float*)d_out;

    float* ws    = (float*)d_ws;
    float* means = ws;                       // 4096 f32
    int*   posidx = (int*)(ws + 4096);       // 2048 i32
    int*   negidx = posidx + 2048;           // 2048 i32
    float* WT    = ws + 4096 + 2048 + 2048;  // 129*128 f32

    k_means<<<BB * CC, 256, 0, stream>>>(x1, means);
    k_select<<<BB, 256, 0, stream>>>(means, eca_w, posidx, negidx);
    k_wt<<<65, 256, 0, stream>>>(conv_w, WT);
    k_main<<<BB * (HW / PIX), 256, 0, stream>>>(x0, x1, WT, posidx, negidx,
                                                bn_gamma, bn_beta, bn_mean, bn_var, out);
}

// Round 8
// 184.204 us; speedup vs baseline: 1.0364x; 1.0364x over previous
//
#include <hip/hip_runtime.h>
#include <math.h>

#define BB 16
#define CC 256
#define HALF 128
#define HW 6400
#define OCH 127   // HALF-1
#define ICH 129   // HALF+1
#define BN_EPS 1e-5f
#define PIX 64    // pixels per block
#define T1S 65    // t1 row stride in f32 (260 B -> bank rotate by 1 per row)

// ---------------- kernel 1: per-(b,c) spatial mean (float4) ----------------
__global__ __launch_bounds__(256) void k_means(const float* __restrict__ x1,
                                               float* __restrict__ means) {
    int bc = blockIdx.x;
    const float4* p = (const float4*)(x1 + (size_t)bc * HW);
    float s = 0.f;
    for (int i = threadIdx.x; i < HW / 4; i += 256) {
        float4 v = p[i];
        s += (v.x + v.y) + (v.z + v.w);
    }
    #pragma unroll
    for (int off = 32; off; off >>= 1) s += __shfl_down(s, off, 64);
    __shared__ float red[4];
    int lane = threadIdx.x & 63, w = threadIdx.x >> 6;
    if (lane == 0) red[w] = s;
    __syncthreads();
    if (threadIdx.x == 0) {
        float t = red[0] + red[1] + red[2] + red[3];
        means[bc] = t * (1.0f / HW);
    }
}

// ---------------- kernel 2: ECA conv + sigmoid + top-k selection ----------------
__global__ __launch_bounds__(256) void k_select(const float* __restrict__ means,
                                                const float* __restrict__ eca_w,
                                                int* __restrict__ posidx,
                                                int* __restrict__ negidx) {
    int b = blockIdx.x;
    int c = threadIdx.x;
    __shared__ float m[CC];
    __shared__ float s[CC];
    __shared__ int flag[CC];
    m[c] = means[b * CC + c];
    __syncthreads();
    float y = 0.f;
    #pragma unroll
    for (int k = 0; k < 5; k++) {
        int cc = c + k - 2;
        float mv = (cc >= 0 && cc < CC) ? m[cc] : 0.f;
        y += eca_w[k] * mv;
    }
    float sc = 1.f / (1.f + expf(-y));
    s[c] = sc;
    __syncthreads();
    int rank = 0;
    for (int j = 0; j < CC; j++) {
        float sj = s[j];
        rank += (sj > sc) || (sj == sc && j < c);
    }
    int ispos = (rank < HALF) ? 1 : 0;
    flag[c] = ispos;
    __syncthreads();
    int pre = 0;
    for (int j = 0; j < c; j++) pre += flag[j];
    if (ispos) posidx[b * HALF + pre] = c;
    else       negidx[b * HALF + (c - pre)] = c;
}

// ---------------- kernel 3: transpose conv_w, pad to 128 cols, zero tail ----
__global__ __launch_bounds__(256) void k_wt(const float* __restrict__ cw,
                                            float* __restrict__ WT) {
    for (int idx = threadIdx.x + blockIdx.x * 256; idx < ICH * 128; idx += 256 * gridDim.x) {
        int i = idx / 128, o = idx % 128;
        WT[idx] = (o < OCH) ? cw[o * ICH + i] : 0.f;
    }
}

// ---------------- kernel 4: main fused kernel (R3 + f32 LDS tmp1) ----------
// 256 threads = 4 waves, 64 pixels/block. Phase A gathers (float4) and stages
// tmp1 rows into LDS as f32 (values already in registers). Phase B: z[32]
// per wave fed by ds_read_b32 (no global latency chain). Phase D as in R3.
__global__ __launch_bounds__(256) void k_main(const float* __restrict__ x0,
                                              const float* __restrict__ x1,
                                              const float* __restrict__ WT,
                                              const int* __restrict__ posidx,
                                              const int* __restrict__ negidx,
                                              const float* __restrict__ bn_gamma,
                                              const float* __restrict__ bn_beta,
                                              const float* __restrict__ bn_mean,
                                              const float* __restrict__ bn_var,
                                              float* __restrict__ out) {
    int blk = blockIdx.x;
    int b = blk / (HW / PIX);
    int tile = blk % (HW / PIX);
    int p0 = tile * PIX;
    int tid = threadIdx.x;
    int q = tid & 15;          // float4 chunk
    int cgrp = tid >> 4;       // 0..15 channel subgroup
    int lane = tid & 63;
    int w = tid >> 6;          // 0..3

    __shared__ float t1[ICH * T1S];     // tmp1 f32, 33.5 KB
    __shared__ float snegA[16 * PIX];   // per-cgrp partial neg sums
    __shared__ float mlds[PIX];         // per-pixel neg mean

    const float* x1b = x1 + (size_t)b * CC * HW;
    const float* x0b = x0 + (size_t)b * CC * HW;
    float* outb = out + (size_t)b * 2 * CC * HW;
    const int* pidx = posidx + b * HALF;
    const int* nidx = negidx + b * HALF;

    // ---- phase A: pos gather + direct + neg gather, all float4;
    //      stage tmp1 rows to LDS from registers ----
    float4 vs = make_float4(0.f, 0.f, 0.f, 0.f);
    #pragma unroll
    for (int s = 0; s < 8; s++) {
        int j = s * 16 + cgrp;
        int cjs = pidx[j];
        int cns = nidx[j];
        const float4* pp = (const float4*)(x1b + (size_t)cjs * HW + p0);
        const float4* pd = (const float4*)(x1b + (size_t)j * HW + p0);
        const float4* pn = (const float4*)(x1b + (size_t)cns * HW + p0);
        float4 vp = pp[q];
        float4 vd = pd[q];
        float4 vn = pn[q];
        float4 so = make_float4(vd.x + vp.x, vd.y + vp.y, vd.z + vp.z, vd.w + vp.w);
        ((float4*)(outb + (size_t)(CC + j) * HW + p0))[q] = so;
        *(float4*)&t1[j * T1S + q * 4] = vp;
        vs.x += vn.x; vs.y += vn.y; vs.z += vn.z; vs.w += vn.w;
    }
    *(float4*)&snegA[cgrp * PIX + q * 4] = vs;
    __syncthreads();

    // ---- neg mean (threads 0..63): t1 row 128, out row CC+HALF ----
    if (tid < 64) {
        float m = 0.f;
        #pragma unroll
        for (int k = 0; k < 16; k++) m += snegA[k * PIX + tid];
        m *= (1.0f / HALF);
        mlds[tid] = m;
        t1[HALF * T1S + tid] = m;
        outb[(size_t)(CC + HALF) * HW + p0 + tid] = x1b[(size_t)HALF * HW + p0 + tid] + m;
    }
    __syncthreads();

    // ---- phase B: z[32] accumulate from LDS (R3 schedule, ds_read feed) ----
    int sg = __builtin_amdgcn_readfirstlane(w);
    const float* wbase = WT + sg * 32;
    int p = p0 + lane;
    float z[32];
    #pragma unroll
    for (int k = 0; k < 32; k++) z[k] = 0.f;
    #pragma unroll 4
    for (int i = 0; i < ICH; i++) {
        float v = t1[i * T1S + lane];          // ds_read_b32, conflict-free
        const float* wc = wbase + i * 128;     // uniform -> s_load
        #pragma unroll
        for (int k = 0; k < 32; k++) z[k] += wc[k] * v;
    }

    // ---- epilogue: BN + leaky + residual for o = sg*32 + k ----
    #pragma unroll
    for (int k = 0; k < 32; k++) {
        int o = sg * 32 + k;
        if (o < OCH) {
            float scale = bn_gamma[o] * rsqrtf(bn_var[o] + BN_EPS);
            float zz = (z[k] - bn_mean[o]) * scale + bn_beta[o];
            float t2 = zz > 0.f ? zz : 0.1f * zz;
            outb[(size_t)(CC + HALF + 1 + o) * HW + p] =
                x1b[(size_t)(HALF + 1 + o) * HW + p] + t2;
        }
    }

    // ---- phase D: x0 copy, float4 (exactly as R3) ----
    #pragma unroll 4
    for (int s = 0; s < 16; s++) {
        int c = s * 16 + cgrp;
        float4 v = ((const float4*)(x0b + (size_t)c * HW + p0))[q];
        ((float4*)(outb + (size_t)c * HW + p0))[q] = v;
    }
}

extern "C" void kernel_launch(void* const* d_in, const int* in_sizes, int n_in,
                              void* d_out, int out_size, void* d_ws, size_t ws_size,
                              hipStream_t stream) {
    const float* x0      = (const float*)d_in[0];
    const float* x1      = (const float*)d_in[1];
    const float* eca_w   = (const float*)d_in[2];
    const float* conv_w  = (const float*)d_in[3];
    const float* bn_gamma= (const float*)d_in[4];
    const float* bn_beta = (const float*)d_in[5];
    const float* bn_mean = (const float*)d_in[6];
    const float* bn_var  = (const float*)d_in[7];
    float* out = (float*)d_out;

    float* ws    = (float*)d_ws;
    float* means = ws;                       // 4096 f32
    int*   posidx = (int*)(ws + 4096);       // 2048 i32
    int*   negidx = posidx + 2048;           // 2048 i32
    float* WT    = ws + 4096 + 2048 + 2048;  // 129*128 f32

    k_means<<<BB * CC, 256, 0, stream>>>(x1, means);
    k_select<<<BB, 256, 0, stream>>>(means, eca_w, posidx, negidx);
    k_wt<<<65, 256, 0, stream>>>(conv_w, WT);
    k_main<<<BB * (HW / PIX), 256, 0, stream>>>(x0, x1, WT, posidx, negidx,
                                                bn_gamma, bn_beta, bn_mean, bn_var, out);
}

// Round 9
// 164.292 us; speedup vs baseline: 1.1620x; 1.1212x over previous
//
#include <hip/hip_runtime.h>
#include <math.h>

#define BB 16
#define CC 256
#define HALF 128
#define HW 6400
#define OCH 127   // HALF-1
#define ICH 129   // HALF+1
#define BN_EPS 1e-5f
#define PIX 64    // pixels per block

// ---------------- kernel 1: per-(b,c) spatial mean (float4) ----------------
__global__ __launch_bounds__(256) void k_means(const float* __restrict__ x1,
                                               float* __restrict__ means) {
    int bc = blockIdx.x;
    const float4* p = (const float4*)(x1 + (size_t)bc * HW);
    float s = 0.f;
    for (int i = threadIdx.x; i < HW / 4; i += 256) {
        float4 v = p[i];
        s += (v.x + v.y) + (v.z + v.w);
    }
    #pragma unroll
    for (int off = 32; off; off >>= 1) s += __shfl_down(s, off, 64);
    __shared__ float red[4];
    int lane = threadIdx.x & 63, w = threadIdx.x >> 6;
    if (lane == 0) red[w] = s;
    __syncthreads();
    if (threadIdx.x == 0) {
        float t = red[0] + red[1] + red[2] + red[3];
        means[bc] = t * (1.0f / HW);
    }
}

// ---------------- kernel 2: ECA conv + sigmoid + top-k selection ----------------
__global__ __launch_bounds__(256) void k_select(const float* __restrict__ means,
                                                const float* __restrict__ eca_w,
                                                int* __restrict__ posidx,
                                                int* __restrict__ negidx) {
    int b = blockIdx.x;
    int c = threadIdx.x;
    __shared__ float m[CC];
    __shared__ float s[CC];
    __shared__ int flag[CC];
    m[c] = means[b * CC + c];
    __syncthreads();
    float y = 0.f;
    #pragma unroll
    for (int k = 0; k < 5; k++) {
        int cc = c + k - 2;
        float mv = (cc >= 0 && cc < CC) ? m[cc] : 0.f;
        y += eca_w[k] * mv;
    }
    float sc = 1.f / (1.f + expf(-y));
    s[c] = sc;
    __syncthreads();
    int rank = 0;
    for (int j = 0; j < CC; j++) {
        float sj = s[j];
        rank += (sj > sc) || (sj == sc && j < c);
    }
    int ispos = (rank < HALF) ? 1 : 0;
    flag[c] = ispos;
    __syncthreads();
    int pre = 0;
    for (int j = 0; j < c; j++) pre += flag[j];
    if (ispos) posidx[b * HALF + pre] = c;
    else       negidx[b * HALF + (c - pre)] = c;
}

// ---------------- kernel 3: transpose conv_w, pad to 128 cols, zero tail ----
__global__ __launch_bounds__(256) void k_wt(const float* __restrict__ cw,
                                            float* __restrict__ WT) {
    for (int idx = threadIdx.x + blockIdx.x * 256; idx < ICH * 128; idx += 256 * gridDim.x) {
        int i = idx / 128, o = idx % 128;
        WT[idx] = (o < OCH) ? cw[o * ICH + i] : 0.f;
    }
}

// ---------------- kernel 4: main fused kernel (R3 + batched-MLP phase B) ----
// 256 threads = 4 waves, 64 pixels/block. Phase B: groups of 8 rows —
// 8 batched index/value loads (8 vmem in flight), then 8x32 FMA drain.
__global__ __launch_bounds__(256) void k_main(const float* __restrict__ x0,
                                              const float* __restrict__ x1,
                                              const float* __restrict__ WT,
                                              const int* __restrict__ posidx,
                                              const int* __restrict__ negidx,
                                              const float* __restrict__ bn_gamma,
                                              const float* __restrict__ bn_beta,
                                              const float* __restrict__ bn_mean,
                                              const float* __restrict__ bn_var,
                                              float* __restrict__ out) {
    int blk = blockIdx.x;
    int b = blk / (HW / PIX);
    int tile = blk % (HW / PIX);
    int p0 = tile * PIX;
    int tid = threadIdx.x;
    int q = tid & 15;          // float4 chunk
    int cgrp = tid >> 4;       // 0..15 channel subgroup
    int lane = tid & 63;
    int w = tid >> 6;          // 0..3

    __shared__ float snegA[16 * PIX];   // per-cgrp partial neg sums
    __shared__ float mlds[PIX];         // per-pixel neg mean

    const float* x1b = x1 + (size_t)b * CC * HW;
    const float* x0b = x0 + (size_t)b * CC * HW;
    float* outb = out + (size_t)b * 2 * CC * HW;
    const int* pidx = posidx + b * HALF;
    const int* nidx = negidx + b * HALF;

    // ---- phase A: pos gather + direct + neg gather, all float4 ----
    float4 vs = make_float4(0.f, 0.f, 0.f, 0.f);
    #pragma unroll
    for (int s = 0; s < 8; s++) {
        int j = s * 16 + cgrp;
        int cjs = pidx[j];
        int cns = nidx[j];
        const float4* pp = (const float4*)(x1b + (size_t)cjs * HW + p0);
        const float4* pd = (const float4*)(x1b + (size_t)j * HW + p0);
        const float4* pn = (const float4*)(x1b + (size_t)cns * HW + p0);
        float4 vp = pp[q];
        float4 vd = pd[q];
        float4 vn = pn[q];
        float4 so = make_float4(vd.x + vp.x, vd.y + vp.y, vd.z + vp.z, vd.w + vp.w);
        ((float4*)(outb + (size_t)(CC + j) * HW + p0))[q] = so;
        vs.x += vn.x; vs.y += vn.y; vs.z += vn.z; vs.w += vn.w;
    }
    *(float4*)&snegA[cgrp * PIX + q * 4] = vs;
    __syncthreads();

    // ---- neg mean (threads 0..63), out row CC+HALF, mean to LDS ----
    if (tid < 64) {
        float m = 0.f;
        #pragma unroll
        for (int k = 0; k < 16; k++) m += snegA[k * PIX + tid];
        m *= (1.0f / HALF);
        mlds[tid] = m;
        outb[(size_t)(CC + HALF) * HW + p0 + tid] = x1b[(size_t)HALF * HW + p0 + tid] + m;
    }
    __syncthreads();

    // ---- phase B: z[32] accumulate, 8-batched loads then FMA drain ----
    int sg = __builtin_amdgcn_readfirstlane(w);
    const float* wbase = WT + sg * 32;
    int p = p0 + lane;
    float z[32];
    #pragma unroll
    for (int k = 0; k < 32; k++) z[k] = 0.f;

    #pragma unroll 1
    for (int s = 0; s < 16; s++) {
        float vb[8];
        #pragma unroll
        for (int u = 0; u < 8; u++) {
            int c = pidx[s * 8 + u];               // batched s_load_dwordx8
            vb[u] = x1b[(size_t)c * HW + p];       // 8 loads in flight
        }
        #pragma unroll
        for (int u = 0; u < 8; u++) {
            const float* wc = wbase + (s * 8 + u) * 128;   // uniform -> s_load
            #pragma unroll
            for (int k = 0; k < 32; k++) z[k] += wc[k] * vb[u];
        }
    }
    {   // mean contribution (input row 128)
        float v = mlds[lane];
        const float* wc = wbase + HALF * 128;
        #pragma unroll
        for (int k = 0; k < 32; k++) z[k] += wc[k] * v;
    }

    // ---- epilogue: BN + leaky + residual for o = sg*32 + k ----
    #pragma unroll
    for (int k = 0; k < 32; k++) {
        int o = sg * 32 + k;
        if (o < OCH) {
            float scale = bn_gamma[o] * rsqrtf(bn_var[o] + BN_EPS);
            float zz = (z[k] - bn_mean[o]) * scale + bn_beta[o];
            float t2 = zz > 0.f ? zz : 0.1f * zz;
            outb[(size_t)(CC + HALF + 1 + o) * HW + p] =
                x1b[(size_t)(HALF + 1 + o) * HW + p] + t2;
        }
    }

    // ---- phase D: x0 copy, float4 ----
    #pragma unroll 4
    for (int s = 0; s < 16; s++) {
        int c = s * 16 + cgrp;
        float4 v = ((const float4*)(x0b + (size_t)c * HW + p0))[q];
        ((float4*)(outb + (size_t)c * HW + p0))[q] = v;
    }
}

extern "C" void kernel_launch(void* const* d_in, const int* in_sizes, int n_in,
                              void* d_out, int out_size, void* d_ws, size_t ws_size,
                              hipStream_t stream) {
    const float* x0      = (const float*)d_in[0];
    const float* x1      = (const float*)d_in[1];
    const float* eca_w   = (const float*)d_in[2];
    const float* conv_w  = (const float*)d_in[3];
    const float* bn_gamma= (const float*)d_in[4];
    const float* bn_beta = (const float*)d_in[5];
    const float* bn_mean = (const float*)d_in[6];
    const float* bn_var  = (const float*)d_in[7];
    float* out = (float*)d_out;

    float* ws    = (float*)d_ws;
    float* means = ws;                       // 4096 f32
    int*   posidx = (int*)(ws + 4096);       // 2048 i32
    int*   negidx = posidx + 2048;           // 2048 i32
    float* WT    = ws + 4096 + 2048 + 2048;  // 129*128 f32

    k_means<<<BB * CC, 256, 0, stream>>>(x1, means);
    k_select<<<BB, 256, 0, stream>>>(means, eca_w, posidx, negidx);
    k_wt<<<65, 256, 0, stream>>>(conv_w, WT);
    k_main<<<BB * (HW / PIX), 256, 0, stream>>>(x0, x1, WT, posidx, negidx,
                                                bn_gamma, bn_beta, bn_mean, bn_var, out);
}

// Round 11
// 136.423 us; speedup vs baseline: 1.3994x; 1.2043x over previous
//
#include <hip/hip_runtime.h>
#include <math.h>

#define BB 16
#define CC 256
#define HALF 128
#define HW 6400
#define OCH 127   // HALF-1
#define ICH 129   // HALF+1
#define BN_EPS 1e-5f
#define PIX 64    // pixels per block

typedef __attribute__((ext_vector_type(8))) short short8v;   // 8 bf16
typedef __attribute__((ext_vector_type(4))) float floatx4;   // MFMA acc

__device__ __forceinline__ unsigned short f2bf(float f) {
    unsigned int u = __float_as_uint(f);
    unsigned int r = (u + 0x7FFFu + ((u >> 16) & 1u)) >> 16;
    return (unsigned short)r;
}

// ---------------- kernel 1: per-(b,c) spatial mean (float4) ----------------
__global__ __launch_bounds__(256) void k_means(const float* __restrict__ x1,
                                               float* __restrict__ means) {
    int bc = blockIdx.x;
    const float4* p = (const float4*)(x1 + (size_t)bc * HW);
    float s = 0.f;
    for (int i = threadIdx.x; i < HW / 4; i += 256) {
        float4 v = p[i];
        s += (v.x + v.y) + (v.z + v.w);
    }
    #pragma unroll
    for (int off = 32; off; off >>= 1) s += __shfl_down(s, off, 64);
    __shared__ float red[4];
    int lane = threadIdx.x & 63, w = threadIdx.x >> 6;
    if (lane == 0) red[w] = s;
    __syncthreads();
    if (threadIdx.x == 0) {
        float t = red[0] + red[1] + red[2] + red[3];
        means[bc] = t * (1.0f / HW);
    }
}

// ---------------- kernel 2: ECA conv + sigmoid + top-k selection ----------------
__global__ __launch_bounds__(256) void k_select(const float* __restrict__ means,
                                                const float* __restrict__ eca_w,
                                                int* __restrict__ posidx,
                                                int* __restrict__ negidx) {
    int b = blockIdx.x;
    int c = threadIdx.x;
    __shared__ float m[CC];
    __shared__ float s[CC];
    __shared__ int flag[CC];
    m[c] = means[b * CC + c];
    __syncthreads();
    float y = 0.f;
    #pragma unroll
    for (int k = 0; k < 5; k++) {
        int cc = c + k - 2;
        float mv = (cc >= 0 && cc < CC) ? m[cc] : 0.f;
        y += eca_w[k] * mv;
    }
    float sc = 1.f / (1.f + expf(-y));
    s[c] = sc;
    __syncthreads();
    int rank = 0;
    for (int j = 0; j < CC; j++) {
        float sj = s[j];
        rank += (sj > sc) || (sj == sc && j < c);
    }
    int ispos = (rank < HALF) ? 1 : 0;
    flag[c] = ispos;
    __syncthreads();
    int pre = 0;
    for (int j = 0; j < c; j++) pre += flag[j];
    if (ispos) posidx[b * HALF + pre] = c;
    else       negidx[b * HALF + (c - pre)] = c;
}

// ---------------- kernel 3: pack W into A-fragment order + BN folding ------
// WB[mt][ks][lane][j] bf16: o = mt*16 + (lane&15), k = ks*32 + (lane>>4)*8 + j
__global__ __launch_bounds__(256) void k_prep(const float* __restrict__ cw,
                                              const float* __restrict__ bn_gamma,
                                              const float* __restrict__ bn_beta,
                                              const float* __restrict__ bn_mean,
                                              const float* __restrict__ bn_var,
                                              unsigned short* __restrict__ WB,
                                              float* __restrict__ w128,
                                              float* __restrict__ bnA,
                                              float* __restrict__ bnB) {
    int idx = blockIdx.x * 256 + threadIdx.x;
    if (idx < 8 * 4 * 64 * 8) {
        int j    = idx & 7;
        int lane = (idx >> 3) & 63;
        int ks   = (idx >> 9) & 3;
        int mt   = idx >> 11;
        int o = mt * 16 + (lane & 15);
        int k = ks * 32 + ((lane >> 4) & 3) * 8 + j;
        float v = (o < OCH) ? cw[o * ICH + k] : 0.f;
        WB[idx] = f2bf(v);
    }
    if (idx < HALF) {
        float a = 0.f, bsh = 0.f, wm = 0.f;
        if (idx < OCH) {
            a   = bn_gamma[idx] * rsqrtf(bn_var[idx] + BN_EPS);
            bsh = bn_beta[idx] - bn_mean[idx] * a;
            wm  = cw[idx * ICH + 128];
        }
        bnA[idx] = a; bnB[idx] = bsh; w128[idx] = wm;
    }
}

// ---------------- kernel 4: main fused kernel (R3 phase A + MFMA phase B) --
// Phase A stages tmp1 bf16 directly in B-fragment order:
//   t1f elem = ((ks*4+nt)*64 + laneT)*8 + jp, XOR-swizzled by (nt<<3),
//   where laneT = (kk>>3)*16 + (p&15), jp = kk&7, kk = k&31, ks = k>>5.
// Phase B: per (ks,nt) one short8v LDS load = the exact B-frag for
// mfma_f32_16x16x32_bf16 (lane: k=(lane>>4)*8+j, n=lane&15).
__global__ __launch_bounds__(256) void k_main(const float* __restrict__ x0,
                                              const float* __restrict__ x1,
                                              const unsigned short* __restrict__ WB,
                                              const float* __restrict__ w128,
                                              const float* __restrict__ bnA,
                                              const float* __restrict__ bnB,
                                              const int* __restrict__ posidx,
                                              const int* __restrict__ negidx,
                                              float* __restrict__ out) {
    int blk = blockIdx.x;
    int b = blk / (HW / PIX);
    int tile = blk % (HW / PIX);
    int p0 = tile * PIX;
    int tid = threadIdx.x;
    int q = tid & 15;          // float4 chunk
    int cgrp = tid >> 4;       // 0..15 channel subgroup
    int lane = tid & 63;
    int w = tid >> 6;          // 0..3

    __shared__ __align__(16) unsigned short t1f[4 * 4 * 64 * 8];  // 16 KB
    __shared__ float snegA[16 * PIX];
    __shared__ float mlds[PIX];
    __shared__ float w128l[HALF], bnAl[HALF], bnBl[HALF];

    const float* x1b = x1 + (size_t)b * CC * HW;
    const float* x0b = x0 + (size_t)b * CC * HW;
    float* outb = out + (size_t)b * 2 * CC * HW;
    const int* pidx = posidx + b * HALF;
    const int* nidx = negidx + b * HALF;

    if (tid < HALF) {
        w128l[tid] = w128[tid];
        bnAl[tid]  = bnA[tid];
        bnBl[tid]  = bnB[tid];
    }

    // ---- phase A: pos gather + direct + neg gather (float4); stage tmp1 ----
    float4 vs = make_float4(0.f, 0.f, 0.f, 0.f);
    #pragma unroll
    for (int s = 0; s < 8; s++) {
        int j = s * 16 + cgrp;                 // k index of this row
        int cjs = pidx[j];
        int cns = nidx[j];
        const float4* pp = (const float4*)(x1b + (size_t)cjs * HW + p0);
        const float4* pd = (const float4*)(x1b + (size_t)j * HW + p0);
        const float4* pn = (const float4*)(x1b + (size_t)cns * HW + p0);
        float4 vp = pp[q];
        float4 vd = pd[q];
        float4 vn = pn[q];
        float4 so = make_float4(vd.x + vp.x, vd.y + vp.y, vd.z + vp.z, vd.w + vp.w);
        ((float4*)(outb + (size_t)(CC + j) * HW + p0))[q] = so;

        // stage into B-frag order (pixels n = q*4 + i)
        int kk  = (s & 1) * 16 + cgrp;         // k & 31
        int ksH = s >> 1;                      // k >> 5
        int ntq = q >> 2;                      // pixel tile
        int laneT = ((kk >> 3) * 16) + (q & 3) * 4;
        unsigned base = (unsigned)((((ksH * 4 + ntq) * 64 + laneT) * 8) + (kk & 7));
        unsigned sw = (unsigned)(ntq << 3);
        t1f[(base + 0 * 8) ^ sw] = f2bf(vp.x);
        t1f[(base + 1 * 8) ^ sw] = f2bf(vp.y);
        t1f[(base + 2 * 8) ^ sw] = f2bf(vp.z);
        t1f[(base + 3 * 8) ^ sw] = f2bf(vp.w);

        vs.x += vn.x; vs.y += vn.y; vs.z += vn.z; vs.w += vn.w;
    }
    *(float4*)&snegA[cgrp * PIX + q * 4] = vs;
    __syncthreads();

    // ---- neg mean (threads 0..63): mlds + out row CC+HALF ----
    if (tid < 64) {
        float m = 0.f;
        #pragma unroll
        for (int k = 0; k < 16; k++) m += snegA[k * PIX + tid];
        m *= (1.0f / HALF);
        mlds[tid] = m;
        outb[(size_t)(CC + HALF) * HW + p0 + tid] = x1b[(size_t)HALF * HW + p0 + tid] + m;
    }
    __syncthreads();

    // ---- phase B: MFMA. wave w owns M-tiles {2w, 2w+1}, all 4 N-tiles ----
    int g_ = lane >> 4;        // row group within C/D frags
    int c_ = lane & 15;        // column (pixel within N-tile)
    floatx4 acc[2][4];
    #pragma unroll
    for (int mi = 0; mi < 2; mi++)
        #pragma unroll
        for (int nt = 0; nt < 4; nt++)
            acc[mi][nt] = (floatx4){0.f, 0.f, 0.f, 0.f};

    const short8v* WBv = (const short8v*)WB;
    const short8v* t1v = (const short8v*)t1f;
    int mt0 = 2 * w, mt1 = 2 * w + 1;

    #pragma unroll
    for (int ks = 0; ks < 4; ks++) {
        short8v a0 = WBv[(mt0 * 4 + ks) * 64 + lane];
        short8v a1 = WBv[(mt1 * 4 + ks) * 64 + lane];
        #pragma unroll
        for (int nt = 0; nt < 4; nt++) {
            short8v bf = t1v[(unsigned)((ks * 4 + nt) * 64 + lane) ^ (unsigned)nt];
            acc[0][nt] = __builtin_amdgcn_mfma_f32_16x16x32_bf16(a0, bf, acc[0][nt], 0, 0, 0);
            acc[1][nt] = __builtin_amdgcn_mfma_f32_16x16x32_bf16(a1, bf, acc[1][nt], 0, 0, 0);
        }
    }

    // ---- epilogue: + mean-row, BN + leaky + residual ----
    float mnv[4];
    #pragma unroll
    for (int nt = 0; nt < 4; nt++) mnv[nt] = mlds[nt * 16 + c_];

    #pragma unroll
    for (int mi = 0; mi < 2; mi++) {
        int mt = 2 * w + mi;
        int obase = mt * 16 + g_ * 4;
        float wmr[4], bAr[4], bBr[4];
        #pragma unroll
        for (int r = 0; r < 4; r++) {
            wmr[r] = w128l[obase + r];
            bAr[r] = bnAl[obase + r];
            bBr[r] = bnBl[obase + r];
        }
        #pragma unroll
        for (int nt = 0; nt < 4; nt++) {
            int p = p0 + nt * 16 + c_;
            #pragma unroll
            for (int r = 0; r < 4; r++) {
                int o = obase + r;
                float zz = acc[mi][nt][r] + wmr[r] * mnv[nt];
                zz = zz * bAr[r] + bBr[r];
                float t2 = zz > 0.f ? zz : 0.1f * zz;
                if (o < OCH) {
                    outb[(size_t)(CC + HALF + 1 + o) * HW + p] =
                        x1b[(size_t)(HALF + 1 + o) * HW + p] + t2;
                }
            }
        }
    }

    // ---- phase D: x0 copy, float4 ----
    #pragma unroll 4
    for (int s = 0; s < 16; s++) {
        int c = s * 16 + cgrp;
        float4 v = ((const float4*)(x0b + (size_t)c * HW + p0))[q];
        ((float4*)(outb + (size_t)c * HW + p0))[q] = v;
    }
}

extern "C" void kernel_launch(void* const* d_in, const int* in_sizes, int n_in,
                              void* d_out, int out_size, void* d_ws, size_t ws_size,
                              hipStream_t stream) {
    const float* x0      = (const float*)d_in[0];
    const float* x1      = (const float*)d_in[1];
    const float* eca_w   = (const float*)d_in[2];
    const float* conv_w  = (const float*)d_in[3];
    const float* bn_gamma= (const float*)d_in[4];
    const float* bn_beta = (const float*)d_in[5];
    const float* bn_mean = (const float*)d_in[6];
    const float* bn_var  = (const float*)d_in[7];
    float* out = (float*)d_out;

    float* ws     = (float*)d_ws;
    float* means  = ws;                          // 4096 f32
    int*   posidx = (int*)(ws + 4096);           // 2048 i32
    int*   negidx = posidx + 2048;               // 2048 i32
    unsigned short* WB = (unsigned short*)(ws + 8192);  // 16384 bf16
    float* w128   = ws + 16384;                  // 128
    float* bnA    = ws + 16512;                  // 128
    float* bnB    = ws + 16640;                  // 128

    k_means<<<BB * CC, 256, 0, stream>>>(x1, means);
    k_select<<<BB, 256, 0, stream>>>(means, eca_w, posidx, negidx);
    k_prep<<<64, 256, 0, stream>>>(conv_w, bn_gamma, bn_beta, bn_mean, bn_var,
                                   WB, w128, bnA, bnB);
    k_main<<<BB * (HW / PIX), 256, 0, stream>>>(x0, x1, WB, w128, bnA, bnB,
                                                posidx, negidx, out);
}

// Round 12
// 125.711 us; speedup vs baseline: 1.5187x; 1.0852x over previous
//
#include <hip/hip_runtime.h>
#include <math.h>

#define BB 16
#define CC 256
#define HALF 128
#define HW 6400
#define OCH 127   // HALF-1
#define ICH 129   // HALF+1
#define BN_EPS 1e-5f
#define PIX 64    // pixels per block
#define T2S 68    // t2 LDS row stride in shorts (136 B, 8B-aligned, bank-spread)

typedef __attribute__((ext_vector_type(8))) short short8v;   // 8 bf16
typedef __attribute__((ext_vector_type(4))) float floatx4;   // MFMA acc

__device__ __forceinline__ unsigned short f2bf(float f) {
    unsigned int u = __float_as_uint(f);
    unsigned int r = (u + 0x7FFFu + ((u >> 16) & 1u)) >> 16;
    return (unsigned short)r;
}
__device__ __forceinline__ float bf2f(unsigned short u) {
    return __uint_as_float((unsigned int)u << 16);
}

// ---------------- kernel 1: per-(b,c) spatial mean (float4) ----------------
__global__ __launch_bounds__(256) void k_means(const float* __restrict__ x1,
                                               float* __restrict__ means) {
    int bc = blockIdx.x;
    const float4* p = (const float4*)(x1 + (size_t)bc * HW);
    float s = 0.f;
    for (int i = threadIdx.x; i < HW / 4; i += 256) {
        float4 v = p[i];
        s += (v.x + v.y) + (v.z + v.w);
    }
    #pragma unroll
    for (int off = 32; off; off >>= 1) s += __shfl_down(s, off, 64);
    __shared__ float red[4];
    int lane = threadIdx.x & 63, w = threadIdx.x >> 6;
    if (lane == 0) red[w] = s;
    __syncthreads();
    if (threadIdx.x == 0) {
        float t = red[0] + red[1] + red[2] + red[3];
        means[bc] = t * (1.0f / HW);
    }
}

// ---------------- kernel 2: ECA conv + sigmoid + top-k selection ----------------
__global__ __launch_bounds__(256) void k_select(const float* __restrict__ means,
                                                const float* __restrict__ eca_w,
                                                int* __restrict__ posidx,
                                                int* __restrict__ negidx) {
    int b = blockIdx.x;
    int c = threadIdx.x;
    __shared__ float m[CC];
    __shared__ float s[CC];
    __shared__ int flag[CC];
    m[c] = means[b * CC + c];
    __syncthreads();
    float y = 0.f;
    #pragma unroll
    for (int k = 0; k < 5; k++) {
        int cc = c + k - 2;
        float mv = (cc >= 0 && cc < CC) ? m[cc] : 0.f;
        y += eca_w[k] * mv;
    }
    float sc = 1.f / (1.f + expf(-y));
    s[c] = sc;
    __syncthreads();
    int rank = 0;
    for (int j = 0; j < CC; j++) {
        float sj = s[j];
        rank += (sj > sc) || (sj == sc && j < c);
    }
    int ispos = (rank < HALF) ? 1 : 0;
    flag[c] = ispos;
    __syncthreads();
    int pre = 0;
    for (int j = 0; j < c; j++) pre += flag[j];
    if (ispos) posidx[b * HALF + pre] = c;
    else       negidx[b * HALF + (c - pre)] = c;
}

// ---------------- kernel 3: pack W into A-fragment order + BN folding ------
// WB[mt][ks][lane][j] bf16: o = mt*16 + (lane&15), k = ks*32 + (lane>>4)*8 + j
__global__ __launch_bounds__(256) void k_prep(const float* __restrict__ cw,
                                              const float* __restrict__ bn_gamma,
                                              const float* __restrict__ bn_beta,
                                              const float* __restrict__ bn_mean,
                                              const float* __restrict__ bn_var,
                                              unsigned short* __restrict__ WB,
                                              float* __restrict__ w128,
                                              float* __restrict__ bnA,
                                              float* __restrict__ bnB) {
    int idx = blockIdx.x * 256 + threadIdx.x;
    if (idx < 8 * 4 * 64 * 8) {
        int j    = idx & 7;
        int lane = (idx >> 3) & 63;
        int ks   = (idx >> 9) & 3;
        int mt   = idx >> 11;
        int o = mt * 16 + (lane & 15);
        int k = ks * 32 + ((lane >> 4) & 3) * 8 + j;
        float v = (o < OCH) ? cw[o * ICH + k] : 0.f;
        WB[idx] = f2bf(v);
    }
    if (idx < HALF) {
        float a = 0.f, bsh = 0.f, wm = 0.f;
        if (idx < OCH) {
            a   = bn_gamma[idx] * rsqrtf(bn_var[idx] + BN_EPS);
            bsh = bn_beta[idx] - bn_mean[idx] * a;
            wm  = cw[idx * ICH + 128];
        }
        bnA[idx] = a; bnB[idx] = bsh; w128[idx] = wm;
    }
}

// ---------------- kernel 4: main fused kernel (R10 + coalesced phase C) ----
__global__ __launch_bounds__(256) void k_main(const float* __restrict__ x0,
                                              const float* __restrict__ x1,
                                              const unsigned short* __restrict__ WB,
                                              const float* __restrict__ w128,
                                              const float* __restrict__ bnA,
                                              const float* __restrict__ bnB,
                                              const int* __restrict__ posidx,
                                              const int* __restrict__ negidx,
                                              float* __restrict__ out) {
    int blk = blockIdx.x;
    int b = blk / (HW / PIX);
    int tile = blk % (HW / PIX);
    int p0 = tile * PIX;
    int tid = threadIdx.x;
    int q = tid & 15;          // float4 chunk
    int cgrp = tid >> 4;       // 0..15 channel subgroup
    int lane = tid & 63;
    int w = tid >> 6;          // 0..3

    // smem aliases: phase A/B = t1f (bf16 B-frags, 16384 B);
    //               phase C   = t2l (bf16 t2, 127*T2S*2 = 17272 B)
    __shared__ __align__(16) unsigned char smem[17280];
    __shared__ float sneg2[4][PIX];
    __shared__ float mlds[PIX];
    __shared__ float w128l[HALF], bnAl[HALF], bnBl[HALF];
    unsigned short* t1f = (unsigned short*)smem;
    unsigned short* t2l = (unsigned short*)smem;

    const float* x1b = x1 + (size_t)b * CC * HW;
    const float* x0b = x0 + (size_t)b * CC * HW;
    float* outb = out + (size_t)b * 2 * CC * HW;
    const int* pidx = posidx + b * HALF;
    const int* nidx = negidx + b * HALF;

    if (tid < HALF) {
        w128l[tid] = w128[tid];
        bnAl[tid]  = bnA[tid];
        bnBl[tid]  = bnB[tid];
    }

    // ---- phase A: pos gather + direct + neg gather (float4); stage tmp1 ----
    float4 vs = make_float4(0.f, 0.f, 0.f, 0.f);
    #pragma unroll
    for (int s = 0; s < 8; s++) {
        int j = s * 16 + cgrp;                 // k index of this row
        int cjs = pidx[j];
        int cns = nidx[j];
        const float4* pp = (const float4*)(x1b + (size_t)cjs * HW + p0);
        const float4* pd = (const float4*)(x1b + (size_t)j * HW + p0);
        const float4* pn = (const float4*)(x1b + (size_t)cns * HW + p0);
        float4 vp = pp[q];
        float4 vd = pd[q];
        float4 vn = pn[q];
        float4 so = make_float4(vd.x + vp.x, vd.y + vp.y, vd.z + vp.z, vd.w + vp.w);
        ((float4*)(outb + (size_t)(CC + j) * HW + p0))[q] = so;

        // stage into B-frag order (pixels n = q*4 + i)
        int kk  = (s & 1) * 16 + cgrp;         // k & 31
        int ksH = s >> 1;                      // k >> 5
        int ntq = q >> 2;                      // pixel tile
        int laneT = ((kk >> 3) * 16) + (q & 3) * 4;
        unsigned base = (unsigned)((((ksH * 4 + ntq) * 64 + laneT) * 8) + (kk & 7));
        unsigned sw = (unsigned)(ntq << 3);
        t1f[(base + 0 * 8) ^ sw] = f2bf(vp.x);
        t1f[(base + 1 * 8) ^ sw] = f2bf(vp.y);
        t1f[(base + 2 * 8) ^ sw] = f2bf(vp.z);
        t1f[(base + 3 * 8) ^ sw] = f2bf(vp.w);

        vs.x += vn.x; vs.y += vn.y; vs.z += vn.z; vs.w += vn.w;
    }
    // in-wave reduce across the wave's 4 cgrps (lanes ^16, ^32)
    #pragma unroll
    for (int off = 16; off <= 32; off <<= 1) {
        vs.x += __shfl_xor(vs.x, off, 64);
        vs.y += __shfl_xor(vs.y, off, 64);
        vs.z += __shfl_xor(vs.z, off, 64);
        vs.w += __shfl_xor(vs.w, off, 64);
    }
    if ((lane >> 4) == 0) *(float4*)&sneg2[w][(lane & 15) * 4] = vs;
    __syncthreads();

    // ---- neg mean (threads 0..63): mlds + out row CC+HALF ----
    if (tid < 64) {
        float m = sneg2[0][tid] + sneg2[1][tid] + sneg2[2][tid] + sneg2[3][tid];
        m *= (1.0f / HALF);
        mlds[tid] = m;
        outb[(size_t)(CC + HALF) * HW + p0 + tid] = x1b[(size_t)HALF * HW + p0 + tid] + m;
    }
    __syncthreads();

    // ---- phase B: MFMA. wave w owns M-tiles {2w, 2w+1}, all 4 N-tiles ----
    int g_ = lane >> 4;        // row group within C/D frags
    int c_ = lane & 15;        // column (pixel within N-tile)
    floatx4 acc[2][4];
    #pragma unroll
    for (int mi = 0; mi < 2; mi++)
        #pragma unroll
        for (int nt = 0; nt < 4; nt++)
            acc[mi][nt] = (floatx4){0.f, 0.f, 0.f, 0.f};

    const short8v* WBv = (const short8v*)WB;
    const short8v* t1v = (const short8v*)t1f;
    int mt0 = 2 * w, mt1 = 2 * w + 1;

    #pragma unroll
    for (int ks = 0; ks < 4; ks++) {
        short8v a0 = WBv[(mt0 * 4 + ks) * 64 + lane];
        short8v a1 = WBv[(mt1 * 4 + ks) * 64 + lane];
        #pragma unroll
        for (int nt = 0; nt < 4; nt++) {
            short8v bf = t1v[(unsigned)((ks * 4 + nt) * 64 + lane) ^ (unsigned)nt];
            acc[0][nt] = __builtin_amdgcn_mfma_f32_16x16x32_bf16(a0, bf, acc[0][nt], 0, 0, 0);
            acc[1][nt] = __builtin_amdgcn_mfma_f32_16x16x32_bf16(a1, bf, acc[1][nt], 0, 0, 0);
        }
    }
    __syncthreads();   // all waves done reading t1f

    // ---- epilogue: + mean-row, BN + leaky; stage t2 bf16 into t2l ----
    float mnv[4];
    #pragma unroll
    for (int nt = 0; nt < 4; nt++) mnv[nt] = mlds[nt * 16 + c_];

    #pragma unroll
    for (int mi = 0; mi < 2; mi++) {
        int mt = 2 * w + mi;
        int obase = mt * 16 + g_ * 4;
        float wmr[4], bAr[4], bBr[4];
        #pragma unroll
        for (int r = 0; r < 4; r++) {
            wmr[r] = w128l[obase + r];
            bAr[r] = bnAl[obase + r];
            bBr[r] = bnBl[obase + r];
        }
        #pragma unroll
        for (int nt = 0; nt < 4; nt++) {
            int px = nt * 16 + c_;
            #pragma unroll
            for (int r = 0; r < 4; r++) {
                int o = obase + r;
                float zz = acc[mi][nt][r] + wmr[r] * mnv[nt];
                zz = zz * bAr[r] + bBr[r];
                float t2 = zz > 0.f ? zz : 0.1f * zz;
                if (o < OCH) t2l[o * T2S + px] = f2bf(t2);
            }
        }
    }
    __syncthreads();

    // ---- phase C: coalesced float4 writes of t2 rows ----
    #pragma unroll
    for (int s = 0; s < 8; s++) {
        int o = s * 16 + cgrp;
        if (o < OCH) {
            ushort4 uv = *(const ushort4*)&t2l[o * T2S + q * 4];
            const float4* px = (const float4*)(x1b + (size_t)(HALF + 1 + o) * HW + p0);
            float4 xv = px[q];
            float4 ov = make_float4(xv.x + bf2f(uv.x), xv.y + bf2f(uv.y),
                                    xv.z + bf2f(uv.z), xv.w + bf2f(uv.w));
            ((float4*)(outb + (size_t)(CC + HALF + 1 + o) * HW + p0))[q] = ov;
        }
    }

    // ---- phase D: x0 copy, float4 ----
    #pragma unroll 4
    for (int s = 0; s < 16; s++) {
        int c = s * 16 + cgrp;
        float4 v = ((const float4*)(x0b + (size_t)c * HW + p0))[q];
        ((float4*)(outb + (size_t)c * HW + p0))[q] = v;
    }
}

extern "C" void kernel_launch(void* const* d_in, const int* in_sizes, int n_in,
                              void* d_out, int out_size, void* d_ws, size_t ws_size,
                              hipStream_t stream) {
    const float* x0      = (const float*)d_in[0];
    const float* x1      = (const float*)d_in[1];
    const float* eca_w   = (const float*)d_in[2];
    const float* conv_w  = (const float*)d_in[3];
    const float* bn_gamma= (const float*)d_in[4];
    const float* bn_beta = (const float*)d_in[5];
    const float* bn_mean = (const float*)d_in[6];
    const float* bn_var  = (const float*)d_in[7];
    float* out = (float*)d_out;

    float* ws     = (float*)d_ws;
    float* means  = ws;                          // 4096 f32
    int*   posidx = (int*)(ws + 4096);           // 2048 i32
    int*   negidx = posidx + 2048;               // 2048 i32
    unsigned short* WB = (unsigned short*)(ws + 8192);  // 16384 bf16
    float* w128   = ws + 16384;                  // 128
    float* bnA    = ws + 16512;                  // 128
    float* bnB    = ws + 16640;                  // 128

    k_means<<<BB * CC, 256, 0, stream>>>(x1, means);
    k_select<<<BB, 256, 0, stream>>>(means, eca_w, posidx, negidx);
    k_prep<<<64, 256, 0, stream>>>(conv_w, bn_gamma, bn_beta, bn_mean, bn_var,
                                   WB, w128, bnA, bnB);
    k_main<<<BB * (HW / PIX), 256, 0, stream>>>(x0, x1, WB, w128, bnA, bnB,
                                                posidx, negidx, out);
}

// Round 13
// 124.419 us; speedup vs baseline: 1.5344x; 1.0104x over previous
//
#include <hip/hip_runtime.h>
#include <math.h>

#define BB 16
#define CC 256
#define HALF 128
#define HW 6400
#define OCH 127   // HALF-1
#define ICH 129   // HALF+1
#define BN_EPS 1e-5f
#define PIX 64    // pixels per block
#define T2S 68    // t2 LDS row stride in shorts (136 B, 8B-aligned, bank-spread)

typedef __attribute__((ext_vector_type(8))) short short8v;   // 8 bf16
typedef __attribute__((ext_vector_type(4))) float floatx4;   // MFMA acc

__device__ __forceinline__ unsigned short f2bf(float f) {
    unsigned int u = __float_as_uint(f);
    unsigned int r = (u + 0x7FFFu + ((u >> 16) & 1u)) >> 16;
    return (unsigned short)r;
}
__device__ __forceinline__ float bf2f(unsigned short u) {
    return __uint_as_float((unsigned int)u << 16);
}

// ---------------- kernel 1: per-(b,c) spatial mean (float4) ----------------
__global__ __launch_bounds__(256) void k_means(const float* __restrict__ x1,
                                               float* __restrict__ means) {
    int bc = blockIdx.x;
    const float4* p = (const float4*)(x1 + (size_t)bc * HW);
    float s = 0.f;
    for (int i = threadIdx.x; i < HW / 4; i += 256) {
        float4 v = p[i];
        s += (v.x + v.y) + (v.z + v.w);
    }
    #pragma unroll
    for (int off = 32; off; off >>= 1) s += __shfl_down(s, off, 64);
    __shared__ float red[4];
    int lane = threadIdx.x & 63, w = threadIdx.x >> 6;
    if (lane == 0) red[w] = s;
    __syncthreads();
    if (threadIdx.x == 0) {
        float t = red[0] + red[1] + red[2] + red[3];
        means[bc] = t * (1.0f / HW);
    }
}

// ---- kernel 2: fused {ECA+sigmoid+topk select | W-pack+BN fold} by block role ----
// blocks 0..15: selection for batch b = blockIdx.x
// blocks 16..79: pack WB (16384 elems) + w128/bnA/bnB (128)
__global__ __launch_bounds__(256) void k_selprep(const float* __restrict__ means,
                                                 const float* __restrict__ eca_w,
                                                 const float* __restrict__ cw,
                                                 const float* __restrict__ bn_gamma,
                                                 const float* __restrict__ bn_beta,
                                                 const float* __restrict__ bn_mean,
                                                 const float* __restrict__ bn_var,
                                                 int* __restrict__ posidx,
                                                 int* __restrict__ negidx,
                                                 unsigned short* __restrict__ WB,
                                                 float* __restrict__ w128,
                                                 float* __restrict__ bnA,
                                                 float* __restrict__ bnB) {
    if (blockIdx.x >= 16) {
        int idx = (int)(blockIdx.x - 16) * 256 + threadIdx.x;   // 0..16383
        {   // WB[mt][ks][lane][j]: o = mt*16+(lane&15), k = ks*32+((lane>>4)&3)*8+j
            int j    = idx & 7;
            int lane = (idx >> 3) & 63;
            int ks   = (idx >> 9) & 3;
            int mt   = idx >> 11;
            int o = mt * 16 + (lane & 15);
            int k = ks * 32 + ((lane >> 4) & 3) * 8 + j;
            float v = (o < OCH) ? cw[o * ICH + k] : 0.f;
            WB[idx] = f2bf(v);
        }
        if (idx < HALF) {
            float a = 0.f, bsh = 0.f, wm = 0.f;
            if (idx < OCH) {
                a   = bn_gamma[idx] * rsqrtf(bn_var[idx] + BN_EPS);
                bsh = bn_beta[idx] - bn_mean[idx] * a;
                wm  = cw[idx * ICH + 128];
            }
            bnA[idx] = a; bnB[idx] = bsh; w128[idx] = wm;
        }
        return;
    }
    int b = blockIdx.x;
    int c = threadIdx.x;
    __shared__ float m[CC];
    __shared__ float s[CC];
    __shared__ int flag[CC];
    m[c] = means[b * CC + c];
    __syncthreads();
    float y = 0.f;
    #pragma unroll
    for (int k = 0; k < 5; k++) {
        int cc = c + k - 2;
        float mv = (cc >= 0 && cc < CC) ? m[cc] : 0.f;
        y += eca_w[k] * mv;
    }
    float sc = 1.f / (1.f + expf(-y));
    s[c] = sc;
    __syncthreads();
    int rank = 0;
    for (int j = 0; j < CC; j++) {
        float sj = s[j];
        rank += (sj > sc) || (sj == sc && j < c);
    }
    int ispos = (rank < HALF) ? 1 : 0;
    flag[c] = ispos;
    __syncthreads();
    int pre = 0;
    for (int j = 0; j < c; j++) pre += flag[j];
    if (ispos) posidx[b * HALF + pre] = c;
    else       negidx[b * HALF + (c - pre)] = c;
}

// ---------------- kernel 3: main fused kernel (R11 + A/D merge) ----------
__global__ __launch_bounds__(256) void k_main(const float* __restrict__ x0,
                                              const float* __restrict__ x1,
                                              const unsigned short* __restrict__ WB,
                                              const float* __restrict__ w128,
                                              const float* __restrict__ bnA,
                                              const float* __restrict__ bnB,
                                              const int* __restrict__ posidx,
                                              const int* __restrict__ negidx,
                                              float* __restrict__ out) {
    int blk = blockIdx.x;
    int b = blk / (HW / PIX);
    int tile = blk % (HW / PIX);
    int p0 = tile * PIX;
    int tid = threadIdx.x;
    int q = tid & 15;          // float4 chunk
    int cgrp = tid >> 4;       // 0..15 channel subgroup
    int lane = tid & 63;
    int w = tid >> 6;          // 0..3

    // smem aliases: phase A/B = t1f (bf16 B-frags); phase C = t2l (bf16 t2)
    __shared__ __align__(16) unsigned char smem[17280];
    __shared__ float sneg2[4][PIX];
    __shared__ float mlds[PIX];
    __shared__ float w128l[HALF], bnAl[HALF], bnBl[HALF];
    unsigned short* t1f = (unsigned short*)smem;
    unsigned short* t2l = (unsigned short*)smem;

    const float* x1b = x1 + (size_t)b * CC * HW;
    const float* x0b = x0 + (size_t)b * CC * HW;
    float* outb = out + (size_t)b * 2 * CC * HW;
    const int* pidx = posidx + b * HALF;
    const int* nidx = negidx + b * HALF;

    if (tid < HALF) {
        w128l[tid] = w128[tid];
        bnAl[tid]  = bnA[tid];
        bnBl[tid]  = bnB[tid];
    }

    // ---- phase A: pos gather + direct + neg gather (float4); stage tmp1;
    //      x0 copy merged in (independent, drains under phase B) ----
    float4 vs = make_float4(0.f, 0.f, 0.f, 0.f);
    #pragma unroll
    for (int s = 0; s < 8; s++) {
        int j = s * 16 + cgrp;                 // k index of this row
        int cjs = pidx[j];
        int cns = nidx[j];
        const float4* pp = (const float4*)(x1b + (size_t)cjs * HW + p0);
        const float4* pd = (const float4*)(x1b + (size_t)j * HW + p0);
        const float4* pn = (const float4*)(x1b + (size_t)cns * HW + p0);
        float4 vp = pp[q];
        float4 vd = pd[q];
        float4 vn = pn[q];
        float4 so = make_float4(vd.x + vp.x, vd.y + vp.y, vd.z + vp.z, vd.w + vp.w);
        ((float4*)(outb + (size_t)(CC + j) * HW + p0))[q] = so;

        // stage into B-frag order (pixels n = q*4 + i)
        int kk  = (s & 1) * 16 + cgrp;         // k & 31
        int ksH = s >> 1;                      // k >> 5
        int ntq = q >> 2;                      // pixel tile
        int laneT = ((kk >> 3) * 16) + (q & 3) * 4;
        unsigned base = (unsigned)((((ksH * 4 + ntq) * 64 + laneT) * 8) + (kk & 7));
        unsigned sw = (unsigned)(ntq << 3);
        t1f[(base + 0 * 8) ^ sw] = f2bf(vp.x);
        t1f[(base + 1 * 8) ^ sw] = f2bf(vp.y);
        t1f[(base + 2 * 8) ^ sw] = f2bf(vp.z);
        t1f[(base + 3 * 8) ^ sw] = f2bf(vp.w);

        vs.x += vn.x; vs.y += vn.y; vs.z += vn.z; vs.w += vn.w;

        // two x0-copy chunks per s-iteration (16 total)
        {
            int c0 = (2 * s) * 16 + cgrp;
            float4 v = ((const float4*)(x0b + (size_t)c0 * HW + p0))[q];
            ((float4*)(outb + (size_t)c0 * HW + p0))[q] = v;
            int c1 = (2 * s + 1) * 16 + cgrp;
            float4 v2 = ((const float4*)(x0b + (size_t)c1 * HW + p0))[q];
            ((float4*)(outb + (size_t)c1 * HW + p0))[q] = v2;
        }
    }
    // in-wave reduce across the wave's 4 cgrps (lanes ^16, ^32)
    #pragma unroll
    for (int off = 16; off <= 32; off <<= 1) {
        vs.x += __shfl_xor(vs.x, off, 64);
        vs.y += __shfl_xor(vs.y, off, 64);
        vs.z += __shfl_xor(vs.z, off, 64);
        vs.w += __shfl_xor(vs.w, off, 64);
    }
    if ((lane >> 4) == 0) *(float4*)&sneg2[w][(lane & 15) * 4] = vs;
    __syncthreads();

    // ---- neg mean (threads 0..63): mlds + out row CC+HALF ----
    if (tid < 64) {
        float m = sneg2[0][tid] + sneg2[1][tid] + sneg2[2][tid] + sneg2[3][tid];
        m *= (1.0f / HALF);
        mlds[tid] = m;
        outb[(size_t)(CC + HALF) * HW + p0 + tid] = x1b[(size_t)HALF * HW + p0 + tid] + m;
    }
    __syncthreads();

    // ---- phase B: MFMA. wave w owns M-tiles {2w, 2w+1}, all 4 N-tiles ----
    int g_ = lane >> 4;        // row group within C/D frags
    int c_ = lane & 15;        // column (pixel within N-tile)
    floatx4 acc[2][4];
    #pragma unroll
    for (int mi = 0; mi < 2; mi++)
        #pragma unroll
        for (int nt = 0; nt < 4; nt++)
            acc[mi][nt] = (floatx4){0.f, 0.f, 0.f, 0.f};

    const short8v* WBv = (const short8v*)WB;
    const short8v* t1v = (const short8v*)t1f;
    int mt0 = 2 * w, mt1 = 2 * w + 1;

    #pragma unroll
    for (int ks = 0; ks < 4; ks++) {
        short8v a0 = WBv[(mt0 * 4 + ks) * 64 + lane];
        short8v a1 = WBv[(mt1 * 4 + ks) * 64 + lane];
        #pragma unroll
        for (int nt = 0; nt < 4; nt++) {
            short8v bf = t1v[(unsigned)((ks * 4 + nt) * 64 + lane) ^ (unsigned)nt];
            acc[0][nt] = __builtin_amdgcn_mfma_f32_16x16x32_bf16(a0, bf, acc[0][nt], 0, 0, 0);
            acc[1][nt] = __builtin_amdgcn_mfma_f32_16x16x32_bf16(a1, bf, acc[1][nt], 0, 0, 0);
        }
    }
    __syncthreads();   // all waves done reading t1f

    // ---- epilogue: + mean-row, BN + leaky; stage t2 bf16 into t2l ----
    float mnv[4];
    #pragma unroll
    for (int nt = 0; nt < 4; nt++) mnv[nt] = mlds[nt * 16 + c_];

    #pragma unroll
    for (int mi = 0; mi < 2; mi++) {
        int mt = 2 * w + mi;
        int obase = mt * 16 + g_ * 4;
        float wmr[4], bAr[4], bBr[4];
        #pragma unroll
        for (int r = 0; r < 4; r++) {
            wmr[r] = w128l[obase + r];
            bAr[r] = bnAl[obase + r];
            bBr[r] = bnBl[obase + r];
        }
        #pragma unroll
        for (int nt = 0; nt < 4; nt++) {
            int px = nt * 16 + c_;
            #pragma unroll
            for (int r = 0; r < 4; r++) {
                int o = obase + r;
                float zz = acc[mi][nt][r] + wmr[r] * mnv[nt];
                zz = zz * bAr[r] + bBr[r];
                float t2 = zz > 0.f ? zz : 0.1f * zz;
                if (o < OCH) t2l[o * T2S + px] = f2bf(t2);
            }
        }
    }
    __syncthreads();

    // ---- phase C: coalesced float4 writes of t2 rows ----
    #pragma unroll
    for (int s = 0; s < 8; s++) {
        int o = s * 16 + cgrp;
        if (o < OCH) {
            ushort4 uv = *(const ushort4*)&t2l[o * T2S + q * 4];
            const float4* px = (const float4*)(x1b + (size_t)(HALF + 1 + o) * HW + p0);
            float4 xv = px[q];
            float4 ov = make_float4(xv.x + bf2f(uv.x), xv.y + bf2f(uv.y),
                                    xv.z + bf2f(uv.z), xv.w + bf2f(uv.w));
            ((float4*)(outb + (size_t)(CC + HALF + 1 + o) * HW + p0))[q] = ov;
        }
    }
}

extern "C" void kernel_launch(void* const* d_in, const int* in_sizes, int n_in,
                              void* d_out, int out_size, void* d_ws, size_t ws_size,
                              hipStream_t stream) {
    const float* x0      = (const float*)d_in[0];
    const float* x1      = (const float*)d_in[1];
    const float* eca_w   = (const float*)d_in[2];
    const float* conv_w  = (const float*)d_in[3];
    const float* bn_gamma= (const float*)d_in[4];
    const float* bn_beta = (const float*)d_in[5];
    const float* bn_mean = (const float*)d_in[6];
    const float* bn_var  = (const float*)d_in[7];
    float* out = (float*)d_out;

    float* ws     = (float*)d_ws;
    float* means  = ws;                          // 4096 f32
    int*   posidx = (int*)(ws + 4096);           // 2048 i32
    int*   negidx = posidx + 2048;               // 2048 i32
    unsigned short* WB = (unsigned short*)(ws + 8192);  // 16384 bf16
    float* w128   = ws + 16384;                  // 128
    float* bnA    = ws + 16512;                  // 128
    float* bnB    = ws + 16640;                  // 128

    k_means<<<BB * CC, 256, 0, stream>>>(x1, means);
    k_selprep<<<80, 256, 0, stream>>>(means, eca_w, conv_w, bn_gamma, bn_beta,
                                      bn_mean, bn_var, posidx, negidx,
                                      WB, w128, bnA, bnB);
    k_main<<<BB * (HW / PIX), 256, 0, stream>>>(x0, x1, WB, w128, bnA, bnB,
                                                posidx, negidx, out);
}

// Round 15
// 115.793 us; speedup vs baseline: 1.6487x; 1.0745x over previous
//
#include <hip/hip_runtime.h>
#include <math.h>

#define BB 16
#define CC 256
#define HALF 128
#define HW 6400
#define OCH 127   // HALF-1
#define ICH 129   // HALF+1
#define BN_EPS 1e-5f
#define PIX 64    // pixels per block
#define T2S 68    // t2 LDS row stride in shorts (136 B, 8B-aligned, bank-spread)

typedef __attribute__((ext_vector_type(8))) short short8v;   // 8 bf16
typedef __attribute__((ext_vector_type(4))) float floatx4;   // MFMA acc / nt vec

__device__ __forceinline__ unsigned short f2bf(float f) {
    unsigned int u = __float_as_uint(f);
    unsigned int r = (u + 0x7FFFu + ((u >> 16) & 1u)) >> 16;
    return (unsigned short)r;
}
__device__ __forceinline__ float bf2f(unsigned short u) {
    return __uint_as_float((unsigned int)u << 16);
}
__device__ __forceinline__ void nt_store4(float* p, float4 v) {
    floatx4 t = {v.x, v.y, v.z, v.w};
    __builtin_nontemporal_store(t, (floatx4*)p);
}
__device__ __forceinline__ float4 nt_load4(const float* p) {
    floatx4 t = __builtin_nontemporal_load((const floatx4*)p);
    return make_float4(t.x, t.y, t.z, t.w);
}

// ---------------- kernel 1: per-(b,c) spatial mean (float4) ----------------
__global__ __launch_bounds__(256) void k_means(const float* __restrict__ x1,
                                               float* __restrict__ means) {
    int bc = blockIdx.x;
    const float4* p = (const float4*)(x1 + (size_t)bc * HW);
    float s = 0.f;
    for (int i = threadIdx.x; i < HW / 4; i += 256) {
        float4 v = p[i];
        s += (v.x + v.y) + (v.z + v.w);
    }
    #pragma unroll
    for (int off = 32; off; off >>= 1) s += __shfl_down(s, off, 64);
    __shared__ float red[4];
    int lane = threadIdx.x & 63, w = threadIdx.x >> 6;
    if (lane == 0) red[w] = s;
    __syncthreads();
    if (threadIdx.x == 0) {
        float t = red[0] + red[1] + red[2] + red[3];
        means[bc] = t * (1.0f / HW);
    }
}

// ---- kernel 2: fused {ECA+sigmoid+topk select | W-pack+BN fold} by block role ----
__global__ __launch_bounds__(256) void k_selprep(const float* __restrict__ means,
                                                 const float* __restrict__ eca_w,
                                                 const float* __restrict__ cw,
                                                 const float* __restrict__ bn_gamma,
                                                 const float* __restrict__ bn_beta,
                                                 const float* __restrict__ bn_mean,
                                                 const float* __restrict__ bn_var,
                                                 int* __restrict__ posidx,
                                                 int* __restrict__ negidx,
                                                 unsigned short* __restrict__ WB,
                                                 float* __restrict__ w128,
                                                 float* __restrict__ bnA,
                                                 float* __restrict__ bnB) {
    if (blockIdx.x >= 16) {
        int idx = (int)(blockIdx.x - 16) * 256 + threadIdx.x;   // 0..16383
        {   // WB[mt][ks][lane][j]: o = mt*16+(lane&15), k = ks*32+((lane>>4)&3)*8+j
            int j    = idx & 7;
            int lane = (idx >> 3) & 63;
            int ks   = (idx >> 9) & 3;
            int mt   = idx >> 11;
            int o = mt * 16 + (lane & 15);
            int k = ks * 32 + ((lane >> 4) & 3) * 8 + j;
            float v = (o < OCH) ? cw[o * ICH + k] : 0.f;
            WB[idx] = f2bf(v);
        }
        if (idx < HALF) {
            float a = 0.f, bsh = 0.f, wm = 0.f;
            if (idx < OCH) {
                a   = bn_gamma[idx] * rsqrtf(bn_var[idx] + BN_EPS);
                bsh = bn_beta[idx] - bn_mean[idx] * a;
                wm  = cw[idx * ICH + 128];
            }
            bnA[idx] = a; bnB[idx] = bsh; w128[idx] = wm;
        }
        return;
    }
    int b = blockIdx.x;
    int c = threadIdx.x;
    __shared__ float m[CC];
    __shared__ __align__(16) float s[CC];
    __shared__ int flag[CC];
    m[c] = means[b * CC + c];
    __syncthreads();
    float y = 0.f;
    #pragma unroll
    for (int k = 0; k < 5; k++) {
        int cc = c + k - 2;
        float mv = (cc >= 0 && cc < CC) ? m[cc] : 0.f;
        y += eca_w[k] * mv;
    }
    float sc = 1.f / (1.f + expf(-y));
    s[c] = sc;
    __syncthreads();
    // rank with lax.top_k tie-break (lower index wins), float4-vectorized scan
    int rank = 0;
    #pragma unroll 4
    for (int j4 = 0; j4 < CC / 4; j4++) {
        float4 sv = *(const float4*)&s[j4 * 4];
        int j = j4 * 4;
        rank += (sv.x > sc) || (sv.x == sc && (j + 0) < c);
        rank += (sv.y > sc) || (sv.y == sc && (j + 1) < c);
        rank += (sv.z > sc) || (sv.z == sc && (j + 2) < c);
        rank += (sv.w > sc) || (sv.w == sc && (j + 3) < c);
    }
    int ispos = (rank < HALF) ? 1 : 0;
    flag[c] = ispos;
    __syncthreads();
    int pre = 0;
    for (int j = 0; j < c; j++) pre += flag[j];
    if (ispos) posidx[b * HALF + pre] = c;
    else       negidx[b * HALF + (c - pre)] = c;
}

// ---------------- kernel 3: main fused kernel (R12 + nontemporal) ----------
__global__ __launch_bounds__(256) void k_main(const float* __restrict__ x0,
                                              const float* __restrict__ x1,
                                              const unsigned short* __restrict__ WB,
                                              const float* __restrict__ w128,
                                              const float* __restrict__ bnA,
                                              const float* __restrict__ bnB,
                                              const int* __restrict__ posidx,
                                              const int* __restrict__ negidx,
                                              float* __restrict__ out) {
    int blk = blockIdx.x;
    int b = blk / (HW / PIX);
    int tile = blk % (HW / PIX);
    int p0 = tile * PIX;
    int tid = threadIdx.x;
    int q = tid & 15;          // float4 chunk
    int cgrp = tid >> 4;       // 0..15 channel subgroup
    int lane = tid & 63;
    int w = tid >> 6;          // 0..3

    // smem aliases: phase A/B = t1f (bf16 B-frags); phase C = t2l (bf16 t2)
    __shared__ __align__(16) unsigned char smem[17280];
    __shared__ float sneg2[4][PIX];
    __shared__ float mlds[PIX];
    __shared__ float w128l[HALF], bnAl[HALF], bnBl[HALF];
    unsigned short* t1f = (unsigned short*)smem;
    unsigned short* t2l = (unsigned short*)smem;

    const float* x1b = x1 + (size_t)b * CC * HW;
    const float* x0b = x0 + (size_t)b * CC * HW;
    float* outb = out + (size_t)b * 2 * CC * HW;
    const int* pidx = posidx + b * HALF;
    const int* nidx = negidx + b * HALF;

    if (tid < HALF) {
        w128l[tid] = w128[tid];
        bnAl[tid]  = bnA[tid];
        bnBl[tid]  = bnB[tid];
    }

    // ---- phase A: pos gather + direct + neg gather (float4); stage tmp1;
    //      x0 copy merged in; all out-stores non-temporal ----
    float4 vs = make_float4(0.f, 0.f, 0.f, 0.f);
    #pragma unroll
    for (int s = 0; s < 8; s++) {
        int j = s * 16 + cgrp;                 // k index of this row
        int cjs = pidx[j];
        int cns = nidx[j];
        const float4* pp = (const float4*)(x1b + (size_t)cjs * HW + p0);
        const float4* pd = (const float4*)(x1b + (size_t)j * HW + p0);
        const float4* pn = (const float4*)(x1b + (size_t)cns * HW + p0);
        float4 vp = pp[q];
        float4 vd = pd[q];
        float4 vn = pn[q];
        float4 so = make_float4(vd.x + vp.x, vd.y + vp.y, vd.z + vp.z, vd.w + vp.w);
        nt_store4(outb + (size_t)(CC + j) * HW + p0 + q * 4, so);

        // stage into B-frag order (pixels n = q*4 + i)
        int kk  = (s & 1) * 16 + cgrp;         // k & 31
        int ksH = s >> 1;                      // k >> 5
        int ntq = q >> 2;                      // pixel tile
        int laneT = ((kk >> 3) * 16) + (q & 3) * 4;
        unsigned base = (unsigned)((((ksH * 4 + ntq) * 64 + laneT) * 8) + (kk & 7));
        unsigned sw = (unsigned)(ntq << 3);
        t1f[(base + 0 * 8) ^ sw] = f2bf(vp.x);
        t1f[(base + 1 * 8) ^ sw] = f2bf(vp.y);
        t1f[(base + 2 * 8) ^ sw] = f2bf(vp.z);
        t1f[(base + 3 * 8) ^ sw] = f2bf(vp.w);

        vs.x += vn.x; vs.y += vn.y; vs.z += vn.z; vs.w += vn.w;

        // two x0-copy chunks per s-iteration (16 total), nt load+store
        {
            int c0 = (2 * s) * 16 + cgrp;
            float4 v = nt_load4(x0b + (size_t)c0 * HW + p0 + q * 4);
            nt_store4(outb + (size_t)c0 * HW + p0 + q * 4, v);
            int c1 = (2 * s + 1) * 16 + cgrp;
            float4 v2 = nt_load4(x0b + (size_t)c1 * HW + p0 + q * 4);
            nt_store4(outb + (size_t)c1 * HW + p0 + q * 4, v2);
        }
    }
    // in-wave reduce across the wave's 4 cgrps (lanes ^16, ^32)
    #pragma unroll
    for (int off = 16; off <= 32; off <<= 1) {
        vs.x += __shfl_xor(vs.x, off, 64);
        vs.y += __shfl_xor(vs.y, off, 64);
        vs.z += __shfl_xor(vs.z, off, 64);
        vs.w += __shfl_xor(vs.w, off, 64);
    }
    if ((lane >> 4) == 0) *(float4*)&sneg2[w][(lane & 15) * 4] = vs;
    __syncthreads();

    // ---- neg mean (threads 0..63): mlds + out row CC+HALF ----
    if (tid < 64) {
        float m = sneg2[0][tid] + sneg2[1][tid] + sneg2[2][tid] + sneg2[3][tid];
        m *= (1.0f / HALF);
        mlds[tid] = m;
        float ov = x1b[(size_t)HALF * HW + p0 + tid] + m;
        __builtin_nontemporal_store(ov, outb + (size_t)(CC + HALF) * HW + p0 + tid);
    }
    __syncthreads();

    // ---- phase B: MFMA. wave w owns M-tiles {2w, 2w+1}, all 4 N-tiles ----
    int g_ = lane >> 4;        // row group within C/D frags
    int c_ = lane & 15;        // column (pixel within N-tile)
    floatx4 acc[2][4];
    #pragma unroll
    for (int mi = 0; mi < 2; mi++)
        #pragma unroll
        for (int nt = 0; nt < 4; nt++)
            acc[mi][nt] = (floatx4){0.f, 0.f, 0.f, 0.f};

    const short8v* WBv = (const short8v*)WB;
    const short8v* t1v = (const short8v*)t1f;
    int mt0 = 2 * w, mt1 = 2 * w + 1;

    #pragma unroll
    for (int ks = 0; ks < 4; ks++) {
        short8v a0 = WBv[(mt0 * 4 + ks) * 64 + lane];
        short8v a1 = WBv[(mt1 * 4 + ks) * 64 + lane];
        #pragma unroll
        for (int nt = 0; nt < 4; nt++) {
            short8v bf = t1v[(unsigned)((ks * 4 + nt) * 64 + lane) ^ (unsigned)nt];
            acc[0][nt] = __builtin_amdgcn_mfma_f32_16x16x32_bf16(a0, bf, acc[0][nt], 0, 0, 0);
            acc[1][nt] = __builtin_amdgcn_mfma_f32_16x16x32_bf16(a1, bf, acc[1][nt], 0, 0, 0);
        }
    }
    __syncthreads();   // all waves done reading t1f

    // ---- epilogue: + mean-row, BN + leaky; stage t2 bf16 into t2l ----
    float mnv[4];
    #pragma unroll
    for (int nt = 0; nt < 4; nt++) mnv[nt] = mlds[nt * 16 + c_];

    #pragma unroll
    for (int mi = 0; mi < 2; mi++) {
        int mt = 2 * w + mi;
        int obase = mt * 16 + g_ * 4;
        float wmr[4], bAr[4], bBr[4];
        #pragma unroll
        for (int r = 0; r < 4; r++) {
            wmr[r] = w128l[obase + r];
            bAr[r] = bnAl[obase + r];
            bBr[r] = bnBl[obase + r];
        }
        #pragma unroll
        for (int nt = 0; nt < 4; nt++) {
            int px = nt * 16 + c_;
            #pragma unroll
            for (int r = 0; r < 4; r++) {
                int o = obase + r;
                float zz = acc[mi][nt][r] + wmr[r] * mnv[nt];
                zz = zz * bAr[r] + bBr[r];
                float t2 = zz > 0.f ? zz : 0.1f * zz;
                if (o < OCH) t2l[o * T2S + px] = f2bf(t2);
            }
        }
    }
    __syncthreads();

    // ---- phase C: coalesced float4 nt-writes of t2 rows ----
    #pragma unroll
    for (int s = 0; s < 8; s++) {
        int o = s * 16 + cgrp;
        if (o < OCH) {
            ushort4 uv = *(const ushort4*)&t2l[o * T2S + q * 4];
            const float4* px = (const float4*)(x1b + (size_t)(HALF + 1 + o) * HW + p0);
            float4 xv = px[q];
            float4 ov = make_float4(xv.x + bf2f(uv.x), xv.y + bf2f(uv.y),
                                    xv.z + bf2f(uv.z), xv.w + bf2f(uv.w));
            nt_store4(outb + (size_t)(CC + HALF + 1 + o) * HW + p0 + q * 4, ov);
        }
    }
}

extern "C" void kernel_launch(void* const* d_in, const int* in_sizes, int n_in,
                              void* d_out, int out_size, void* d_ws, size_t ws_size,
                              hipStream_t stream) {
    const float* x0      = (const float*)d_in[0];
    const float* x1      = (const float*)d_in[1];
    const float* eca_w   = (const float*)d_in[2];
    const float* conv_w  = (const float*)d_in[3];
    const float* bn_gamma= (const float*)d_in[4];
    const float* bn_beta = (const float*)d_in[5];
    const float* bn_mean = (const float*)d_in[6];
    const float* bn_var  = (const float*)d_in[7];
    float* out = (float*)d_out;

    float* ws     = (float*)d_ws;
    float* means  = ws;                          // 4096 f32
    int*   posidx = (int*)(ws + 4096);           // 2048 i32
    int*   negidx = posidx + 2048;               // 2048 i32
    unsigned short* WB = (unsigned short*)(ws + 8192);  // 16384 bf16
    float* w128   = ws + 16384;                  // 128
    float* bnA    = ws + 16512;                  // 128
    float* bnB    = ws + 16640;                  // 128

    k_means<<<BB * CC, 256, 0, stream>>>(x1, means);
    k_selprep<<<80, 256, 0, stream>>>(means, eca_w, conv_w, bn_gamma, bn_beta,
                                      bn_mean, bn_var, posidx, negidx,
                                      WB, w128, bnA, bnB);
    k_main<<<BB * (HW / PIX), 256, 0, stream>>>(x0, x1, WB, w128, bnA, bnB,
                                                posidx, negidx, out);
}

// Round 16
// 114.648 us; speedup vs baseline: 1.6652x; 1.0100x over previous
//
#include <hip/hip_runtime.h>
#include <math.h>

#define BB 16
#define CC 256
#define HALF 128
#define HW 6400
#define OCH 127   // HALF-1
#define ICH 129   // HALF+1
#define BN_EPS 1e-5f
#define PIX 64    // pixels per block
#define T2S 68    // t2 LDS row stride in shorts (136 B, 8B-aligned, bank-spread)

typedef __attribute__((ext_vector_type(8))) short short8v;   // 8 bf16
typedef __attribute__((ext_vector_type(4))) float floatx4;   // MFMA acc / nt vec

__device__ __forceinline__ unsigned short f2bf(float f) {
    unsigned int u = __float_as_uint(f);
    unsigned int r = (u + 0x7FFFu + ((u >> 16) & 1u)) >> 16;
    return (unsigned short)r;
}
__device__ __forceinline__ float bf2f(unsigned short u) {
    return __uint_as_float((unsigned int)u << 16);
}
__device__ __forceinline__ void nt_store4(float* p, float4 v) {
    floatx4 t = {v.x, v.y, v.z, v.w};
    __builtin_nontemporal_store(t, (floatx4*)p);
}
__device__ __forceinline__ float4 nt_load4(const float* p) {
    floatx4 t = __builtin_nontemporal_load((const floatx4*)p);
    return make_float4(t.x, t.y, t.z, t.w);
}

// ---------------- kernel 1: per-(b,c) spatial mean (float4) ----------------
__global__ __launch_bounds__(256) void k_means(const float* __restrict__ x1,
                                               float* __restrict__ means) {
    int bc = blockIdx.x;
    const float4* p = (const float4*)(x1 + (size_t)bc * HW);
    float s = 0.f;
    for (int i = threadIdx.x; i < HW / 4; i += 256) {
        float4 v = p[i];
        s += (v.x + v.y) + (v.z + v.w);
    }
    #pragma unroll
    for (int off = 32; off; off >>= 1) s += __shfl_down(s, off, 64);
    __shared__ float red[4];
    int lane = threadIdx.x & 63, w = threadIdx.x >> 6;
    if (lane == 0) red[w] = s;
    __syncthreads();
    if (threadIdx.x == 0) {
        float t = red[0] + red[1] + red[2] + red[3];
        means[bc] = t * (1.0f / HW);
    }
}

// ---- kernel 2: fused {ECA+sigmoid+topk select | W-pack+BN fold} by block role ----
__global__ __launch_bounds__(256) void k_selprep(const float* __restrict__ means,
                                                 const float* __restrict__ eca_w,
                                                 const float* __restrict__ cw,
                                                 const float* __restrict__ bn_gamma,
                                                 const float* __restrict__ bn_beta,
                                                 const float* __restrict__ bn_mean,
                                                 const float* __restrict__ bn_var,
                                                 int* __restrict__ posidx,
                                                 int* __restrict__ negidx,
                                                 unsigned short* __restrict__ WB,
                                                 float* __restrict__ w128,
                                                 float* __restrict__ bnA,
                                                 float* __restrict__ bnB) {
    if (blockIdx.x >= 16) {
        int idx = (int)(blockIdx.x - 16) * 256 + threadIdx.x;   // 0..16383
        {   // WB[mt][ks][lane][j]: o = mt*16+(lane&15), k = ks*32+((lane>>4)&3)*8+j
            int j    = idx & 7;
            int lane = (idx >> 3) & 63;
            int ks   = (idx >> 9) & 3;
            int mt   = idx >> 11;
            int o = mt * 16 + (lane & 15);
            int k = ks * 32 + ((lane >> 4) & 3) * 8 + j;
            float v = (o < OCH) ? cw[o * ICH + k] : 0.f;
            WB[idx] = f2bf(v);
        }
        if (idx < HALF) {
            float a = 0.f, bsh = 0.f, wm = 0.f;
            if (idx < OCH) {
                a   = bn_gamma[idx] * rsqrtf(bn_var[idx] + BN_EPS);
                bsh = bn_beta[idx] - bn_mean[idx] * a;
                wm  = cw[idx * ICH + 128];
            }
            bnA[idx] = a; bnB[idx] = bsh; w128[idx] = wm;
        }
        return;
    }
    int b = blockIdx.x;
    int c = threadIdx.x;
    __shared__ float m[CC];
    __shared__ __align__(16) float s[CC];
    __shared__ int flag[CC];
    m[c] = means[b * CC + c];
    __syncthreads();
    float y = 0.f;
    #pragma unroll
    for (int k = 0; k < 5; k++) {
        int cc = c + k - 2;
        float mv = (cc >= 0 && cc < CC) ? m[cc] : 0.f;
        y += eca_w[k] * mv;
    }
    float sc = 1.f / (1.f + expf(-y));
    s[c] = sc;
    __syncthreads();
    // rank with lax.top_k tie-break (lower index wins), float4-vectorized scan
    int rank = 0;
    #pragma unroll 4
    for (int j4 = 0; j4 < CC / 4; j4++) {
        float4 sv = *(const float4*)&s[j4 * 4];
        int j = j4 * 4;
        rank += (sv.x > sc) || (sv.x == sc && (j + 0) < c);
        rank += (sv.y > sc) || (sv.y == sc && (j + 1) < c);
        rank += (sv.z > sc) || (sv.z == sc && (j + 2) < c);
        rank += (sv.w > sc) || (sv.w == sc && (j + 3) < c);
    }
    int ispos = (rank < HALF) ? 1 : 0;
    flag[c] = ispos;
    __syncthreads();
    int pre = 0;
    for (int j = 0; j < c; j++) pre += flag[j];
    if (ispos) posidx[b * HALF + pre] = c;
    else       negidx[b * HALF + (c - pre)] = c;
}

// ---------------- kernel 3: main fused kernel (R14 + LDS trim -> 8 blk/CU) --
__global__ __launch_bounds__(256) void k_main(const float* __restrict__ x0,
                                              const float* __restrict__ x1,
                                              const unsigned short* __restrict__ WB,
                                              const float* __restrict__ w128,
                                              const float* __restrict__ bnA,
                                              const float* __restrict__ bnB,
                                              const int* __restrict__ posidx,
                                              const int* __restrict__ negidx,
                                              float* __restrict__ out) {
    int blk = blockIdx.x;
    int b = blk / (HW / PIX);
    int tile = blk % (HW / PIX);
    int p0 = tile * PIX;
    int tid = threadIdx.x;
    int q = tid & 15;          // float4 chunk
    int cgrp = tid >> 4;       // 0..15 channel subgroup
    int lane = tid & 63;
    int w = tid >> 6;          // 0..3

    // smem aliases: phase A/B = t1f (bf16 B-frags); phase C = t2l (bf16 t2)
    __shared__ __align__(16) unsigned char smem[17280];
    __shared__ float sneg2[4][PIX];
    __shared__ float mlds[PIX];
    unsigned short* t1f = (unsigned short*)smem;
    unsigned short* t2l = (unsigned short*)smem;

    const float* x1b = x1 + (size_t)b * CC * HW;
    const float* x0b = x0 + (size_t)b * CC * HW;
    float* outb = out + (size_t)b * 2 * CC * HW;
    const int* pidx = posidx + b * HALF;
    const int* nidx = negidx + b * HALF;

    // ---- phase A: pos gather + direct + neg gather (float4); stage tmp1;
    //      x0 copy merged in; all out-stores non-temporal ----
    float4 vs = make_float4(0.f, 0.f, 0.f, 0.f);
    #pragma unroll
    for (int s = 0; s < 8; s++) {
        int j = s * 16 + cgrp;                 // k index of this row
        int cjs = pidx[j];
        int cns = nidx[j];
        const float4* pp = (const float4*)(x1b + (size_t)cjs * HW + p0);
        const float4* pd = (const float4*)(x1b + (size_t)j * HW + p0);
        const float4* pn = (const float4*)(x1b + (size_t)cns * HW + p0);
        float4 vp = pp[q];
        float4 vd = pd[q];
        float4 vn = pn[q];
        float4 so = make_float4(vd.x + vp.x, vd.y + vp.y, vd.z + vp.z, vd.w + vp.w);
        nt_store4(outb + (size_t)(CC + j) * HW + p0 + q * 4, so);

        // stage into B-frag order (pixels n = q*4 + i)
        int kk  = (s & 1) * 16 + cgrp;         // k & 31
        int ksH = s >> 1;                      // k >> 5
        int ntq = q >> 2;                      // pixel tile
        int laneT = ((kk >> 3) * 16) + (q & 3) * 4;
        unsigned base = (unsigned)((((ksH * 4 + ntq) * 64 + laneT) * 8) + (kk & 7));
        unsigned sw = (unsigned)(ntq << 3);
        t1f[(base + 0 * 8) ^ sw] = f2bf(vp.x);
        t1f[(base + 1 * 8) ^ sw] = f2bf(vp.y);
        t1f[(base + 2 * 8) ^ sw] = f2bf(vp.z);
        t1f[(base + 3 * 8) ^ sw] = f2bf(vp.w);

        vs.x += vn.x; vs.y += vn.y; vs.z += vn.z; vs.w += vn.w;

        // two x0-copy chunks per s-iteration (16 total), nt load+store
        {
            int c0 = (2 * s) * 16 + cgrp;
            float4 v = nt_load4(x0b + (size_t)c0 * HW + p0 + q * 4);
            nt_store4(outb + (size_t)c0 * HW + p0 + q * 4, v);
            int c1 = (2 * s + 1) * 16 + cgrp;
            float4 v2 = nt_load4(x0b + (size_t)c1 * HW + p0 + q * 4);
            nt_store4(outb + (size_t)c1 * HW + p0 + q * 4, v2);
        }
    }
    // in-wave reduce across the wave's 4 cgrps (lanes ^16, ^32)
    #pragma unroll
    for (int off = 16; off <= 32; off <<= 1) {
        vs.x += __shfl_xor(vs.x, off, 64);
        vs.y += __shfl_xor(vs.y, off, 64);
        vs.z += __shfl_xor(vs.z, off, 64);
        vs.w += __shfl_xor(vs.w, off, 64);
    }
    if ((lane >> 4) == 0) *(float4*)&sneg2[w][(lane & 15) * 4] = vs;
    __syncthreads();

    // ---- neg mean (threads 0..63): mlds + out row CC+HALF ----
    if (tid < 64) {
        float m = sneg2[0][tid] + sneg2[1][tid] + sneg2[2][tid] + sneg2[3][tid];
        m *= (1.0f / HALF);
        mlds[tid] = m;
        float ov = x1b[(size_t)HALF * HW + p0 + tid] + m;
        __builtin_nontemporal_store(ov, outb + (size_t)(CC + HALF) * HW + p0 + tid);
    }
    __syncthreads();

    // ---- phase B: MFMA. wave w owns M-tiles {2w, 2w+1}, all 4 N-tiles ----
    int g_ = lane >> 4;        // row group within C/D frags
    int c_ = lane & 15;        // column (pixel within N-tile)
    floatx4 acc[2][4];
    #pragma unroll
    for (int mi = 0; mi < 2; mi++)
        #pragma unroll
        for (int nt = 0; nt < 4; nt++)
            acc[mi][nt] = (floatx4){0.f, 0.f, 0.f, 0.f};

    const short8v* WBv = (const short8v*)WB;
    const short8v* t1v = (const short8v*)t1f;
    int mt0 = 2 * w, mt1 = 2 * w + 1;

    #pragma unroll
    for (int ks = 0; ks < 4; ks++) {
        short8v a0 = WBv[(mt0 * 4 + ks) * 64 + lane];
        short8v a1 = WBv[(mt1 * 4 + ks) * 64 + lane];
        #pragma unroll
        for (int nt = 0; nt < 4; nt++) {
            short8v bf = t1v[(unsigned)((ks * 4 + nt) * 64 + lane) ^ (unsigned)nt];
            acc[0][nt] = __builtin_amdgcn_mfma_f32_16x16x32_bf16(a0, bf, acc[0][nt], 0, 0, 0);
            acc[1][nt] = __builtin_amdgcn_mfma_f32_16x16x32_bf16(a1, bf, acc[1][nt], 0, 0, 0);
        }
    }
    __syncthreads();   // all waves done reading t1f

    // ---- epilogue: + mean-row, BN + leaky; stage t2 bf16 into t2l ----
    // (BN tables read straight from global: 128-float tables, L1/L2-hot)
    float mnv[4];
    #pragma unroll
    for (int nt = 0; nt < 4; nt++) mnv[nt] = mlds[nt * 16 + c_];

    #pragma unroll
    for (int mi = 0; mi < 2; mi++) {
        int mt = 2 * w + mi;
        int obase = mt * 16 + g_ * 4;
        float wmr[4], bAr[4], bBr[4];
        #pragma unroll
        for (int r = 0; r < 4; r++) {
            wmr[r] = w128[obase + r];
            bAr[r] = bnA[obase + r];
            bBr[r] = bnB[obase + r];
        }
        #pragma unroll
        for (int nt = 0; nt < 4; nt++) {
            int px = nt * 16 + c_;
            #pragma unroll
            for (int r = 0; r < 4; r++) {
                int o = obase + r;
                float zz = acc[mi][nt][r] + wmr[r] * mnv[nt];
                zz = zz * bAr[r] + bBr[r];
                float t2 = zz > 0.f ? zz : 0.1f * zz;
                if (o < OCH) t2l[o * T2S + px] = f2bf(t2);
            }
        }
    }
    __syncthreads();

    // ---- phase C: coalesced float4 nt-writes of t2 rows ----
    #pragma unroll
    for (int s = 0; s < 8; s++) {
        int o = s * 16 + cgrp;
        if (o < OCH) {
            ushort4 uv = *(const ushort4*)&t2l[o * T2S + q * 4];
            const float4* px = (const float4*)(x1b + (size_t)(HALF + 1 + o) * HW + p0);
            float4 xv = px[q];
            float4 ov = make_float4(xv.x + bf2f(uv.x), xv.y + bf2f(uv.y),
                                    xv.z + bf2f(uv.z), xv.w + bf2f(uv.w));
            nt_store4(outb + (size_t)(CC + HALF + 1 + o) * HW + p0 + q * 4, ov);
        }
    }
}

extern "C" void kernel_launch(void* const* d_in, const int* in_sizes, int n_in,
                              void* d_out, int out_size, void* d_ws, size_t ws_size,
                              hipStream_t stream) {
    const float* x0      = (const float*)d_in[0];
    const float* x1      = (const float*)d_in[1];
    const float* eca_w   = (const float*)d_in[2];
    const float* conv_w  = (const float*)d_in[3];
    const float* bn_gamma= (const float*)d_in[4];
    const float* bn_beta = (const float*)d_in[5];
    const float* bn_mean = (const float*)d_in[6];
    const float* bn_var  = (const float*)d_in[7];
    float* out = (float*)d_out;

    float* ws     = (float*)d_ws;
    float* means  = ws;                          // 4096 f32
    int*   posidx = (int*)(ws + 4096);           // 2048 i32
    int*   negidx = posidx + 2048;               // 2048 i32
    unsigned short* WB = (unsigned short*)(ws + 8192);  // 16384 bf16
    float* w128   = ws + 16384;                  // 128
    float* bnA    = ws + 16512;                  // 128
    float* bnB    = ws + 16640;                  // 128

    k_means<<<BB * CC, 256, 0, stream>>>(x1, means);
    k_selprep<<<80, 256, 0, stream>>>(means, eca_w, conv_w, bn_gamma, bn_beta,
                                      bn_mean, bn_var, posidx, negidx,
                                      WB, w128, bnA, bnB);
    k_main<<<BB * (HW / PIX), 256, 0, stream>>>(x0, x1, WB, w128, bnA, bnB,
                                                posidx, negidx, out);
}